// Round 1
// baseline (1179.049 us; speedup 1.0000x reference)
//
#include <hip/hip_runtime.h>
#include <math.h>

#define D 128
#define H 8
#define NGT 8
#define LSTOK 4   // n_global_tokens_global (fixed by problem)

__device__ __forceinline__ float dot4(float4 a, float4 b) {
  return a.x*b.x + a.y*b.y + a.z*b.z + a.w*b.w;
}
__device__ __forceinline__ float4 scale_madd(float4 a, float sc, float4 v, float p) {
  return make_float4(fmaf(p, v.x, a.x*sc), fmaf(p, v.y, a.y*sc),
                     fmaf(p, v.z, a.z*sc), fmaf(p, v.w, a.w*sc));
}
__device__ __forceinline__ float4 comb4(float4 a, float e1, float4 c, float e2) {
  return make_float4(a.x*e1 + c.x*e2, a.y*e1 + c.y*e2, a.z*e1 + c.z*e2, a.w*e1 + c.w*e2);
}
__device__ __forceinline__ float4 shfl_xor4(float4 v, int off) {
  return make_float4(__shfl_xor(v.x, off), __shfl_xor(v.y, off),
                     __shfl_xor(v.z, off), __shfl_xor(v.w, off));
}

// ---------------- GEMM: out[n][c] = sum_k A[n][k]*W[c][k] + bias[c] ----------------
// 64-row x 128-col tile per block of 256 threads; A staged in LDS; W via L1/L2.
template<int K>
__global__ void __launch_bounds__(256) gemm_nt(const float* __restrict__ A,
    const float* __restrict__ W, const float* __restrict__ bias,
    float* __restrict__ out, int Nrows, int Ccols, int relu)
{
  __shared__ float xs[64][K];
  const int t = threadIdx.x;
  const int rowBase = blockIdx.x * 64;
  for (int idx = t * 4; idx < 64 * K; idx += 1024) {
    int r = idx / K, c = idx % K;
    float4 v = make_float4(0.f, 0.f, 0.f, 0.f);
    int gr = rowBase + r;
    if (gr < Nrows) v = *(const float4*)(A + (size_t)gr * K + c);
    *(float4*)&xs[r][c] = v;
  }
  __syncthreads();
  const int tc = t & 31, tr = t >> 5;
  const int c0 = blockIdx.y * 128 + tc * 4;
  const int r0 = tr * 8;
  float acc[8][4];
#pragma unroll
  for (int i = 0; i < 8; i++) { acc[i][0] = 0.f; acc[i][1] = 0.f; acc[i][2] = 0.f; acc[i][3] = 0.f; }
  const float* w0p = W + (size_t)c0 * K;
  for (int k = 0; k < K; k += 4) {
    float4 w0 = *(const float4*)(w0p + k);
    float4 w1 = *(const float4*)(w0p + K + k);
    float4 w2 = *(const float4*)(w0p + 2 * K + k);
    float4 w3 = *(const float4*)(w0p + 3 * K + k);
#pragma unroll
    for (int i = 0; i < 8; i++) {
      float4 xv = *(const float4*)&xs[r0 + i][k];
      acc[i][0] += dot4(xv, w0);
      acc[i][1] += dot4(xv, w1);
      acc[i][2] += dot4(xv, w2);
      acc[i][3] += dot4(xv, w3);
    }
  }
  float bb0 = bias[c0], bb1 = bias[c0 + 1], bb2 = bias[c0 + 2], bb3 = bias[c0 + 3];
#pragma unroll
  for (int i = 0; i < 8; i++) {
    int gr = rowBase + r0 + i;
    if (gr >= Nrows) break;
    float4 o = make_float4(acc[i][0] + bb0, acc[i][1] + bb1, acc[i][2] + bb2, acc[i][3] + bb3);
    if (relu) { o.x = fmaxf(o.x, 0.f); o.y = fmaxf(o.y, 0.f); o.z = fmaxf(o.z, 0.f); o.w = fmaxf(o.w, 0.f); }
    *(float4*)(out + (size_t)gr * Ccols + c0) = o;
  }
}

// small GEMM (M rows <= 64, K=C=128): one block per row
__global__ void gemm_small(const float* __restrict__ A, const float* __restrict__ W,
                           const float* __restrict__ bias, float* __restrict__ out, int M)
{
  int r = blockIdx.x;
  int c = threadIdx.x;
  __shared__ float as[128];
  as[c] = A[(size_t)r * 128 + c];
  __syncthreads();
  float acc = bias[c];
  const float* wr = W + (size_t)c * 128;
#pragma unroll 4
  for (int k = 0; k < 128; k++) acc += as[k] * wr[k];
  out[(size_t)r * 128 + c] = acc;
}

// ---------------- CSR build ----------------
__global__ void count_deg(const int* __restrict__ dst, int* __restrict__ deg, int E) {
  int e = blockIdx.x * 256 + threadIdx.x;
  if (e < E) atomicAdd(&deg[dst[e]], 1);
}

__global__ void scan_kernel(const int* __restrict__ deg, int* __restrict__ row_start,
                            int* __restrict__ cursor, int N, int E)
{
  __shared__ int sh[1024];
  int t = threadIdx.x;
  int chunk = (N + 1023) >> 10;
  int b0 = t * chunk;
  int b1 = b0 + chunk; if (b1 > N) b1 = N;
  int s = 0;
  for (int i = b0; i < b1 && i < N; i++) s += deg[i];
  sh[t] = s;
  __syncthreads();
  for (int off = 1; off < 1024; off <<= 1) {
    int v = (t >= off) ? sh[t - off] : 0;
    __syncthreads();
    sh[t] += v;
    __syncthreads();
  }
  int base = (t == 0) ? 0 : sh[t - 1];
  for (int i = b0; i < b1 && i < N; i++) {
    row_start[i] = base; cursor[i] = base; base += deg[i];
  }
  if (t == 1023) row_start[N] = E;
}

__global__ void fill_edges(const int* __restrict__ dst, int* __restrict__ cursor,
                           int* __restrict__ edge_list, int E) {
  int e = blockIdx.x * 256 + threadIdx.x;
  if (e < E) {
    int p = atomicAdd(&cursor[dst[e]], 1);
    edge_list[p] = e;
  }
}

// ---------------- tconv edge attention: one thread per (node, head), online softmax ----------------
__global__ void tconv_attn(const float* __restrict__ q_all, const float* __restrict__ k_all,
                           const float* __restrict__ v_all, const int* __restrict__ row_start,
                           const int* __restrict__ edge_list, const int* __restrict__ srcI,
                           float* __restrict__ out, int N)
{
  int gid = blockIdx.x * 256 + threadIdx.x;
  if (gid >= N * H) return;
  int n = gid >> 3, h = gid & 7;
  size_t qb = (size_t)n * 128 + h * 16;
  const float4* q4 = (const float4*)(q_all + qb);
  float4 q0 = q4[0], q1 = q4[1], q2 = q4[2], q3 = q4[3];
  float m = -3.0e38f, s = 0.f;
  float4 a0 = make_float4(0, 0, 0, 0), a1 = a0, a2 = a0, a3 = a0;
  int e1 = row_start[n + 1];
  for (int ei = row_start[n]; ei < e1; ei++) {
    int sn = srcI[edge_list[ei]];
    size_t kb = (size_t)sn * 128 + h * 16;
    const float4* k4 = (const float4*)(k_all + kb);
    float d = dot4(q0, k4[0]) + dot4(q1, k4[1]) + dot4(q2, k4[2]) + dot4(q3, k4[3]);
    d *= 0.25f;
    float mn = fmaxf(m, d);
    float sc = expf(m - mn);
    float p = expf(d - mn);
    const float4* v4 = (const float4*)(v_all + kb);
    a0 = scale_madd(a0, sc, v4[0], p);
    a1 = scale_madd(a1, sc, v4[1], p);
    a2 = scale_madd(a2, sc, v4[2], p);
    a3 = scale_madd(a3, sc, v4[3], p);
    s = s * sc + p;
    m = mn;
  }
  float inv = 1.f / (s + 1e-16f);
  float4* o4 = (float4*)(out + qb);
  o4[0] = make_float4(a0.x * inv, a0.y * inv, a0.z * inv, a0.w * inv);
  o4[1] = make_float4(a1.x * inv, a1.y * inv, a1.z * inv, a1.w * inv);
  o4[2] = make_float4(a2.x * inv, a2.y * inv, a2.z * inv, a2.w * inv);
  o4[3] = make_float4(a3.x * inv, a3.y * inv, a3.z * inv, a3.w * inv);
}

// ---------------- gate (sigmoid beta) + residual + LN; one wave per node ----------------
__global__ void gate_ln(const float* __restrict__ x, const float* __restrict__ att,
                        const float* __restrict__ xr, const float* __restrict__ Wb,
                        float* __restrict__ x1, int N)
{
  int wid = threadIdx.x >> 6, lane = threadIdx.x & 63;
  int n = blockIdx.x * 4 + wid;
  if (n >= N) return;
  size_t base = (size_t)n * 128 + lane * 2;
  float2 o = *(const float2*)(att + base);
  float2 r = *(const float2*)(xr + base);
  float2 xv = *(const float2*)(x + base);
  float2 w0 = *(const float2*)(Wb + lane * 2);
  float2 w1 = *(const float2*)(Wb + 128 + lane * 2);
  float2 w2 = *(const float2*)(Wb + 256 + lane * 2);
  float ts = o.x * w0.x + o.y * w0.y + r.x * w1.x + r.y * w1.y
           + (o.x - r.x) * w2.x + (o.y - r.y) * w2.y;
#pragma unroll
  for (int mm = 32; mm >= 1; mm >>= 1) ts += __shfl_xor(ts, mm);
  float beta = 1.f / (1.f + expf(-ts));
  float2 y;
  y.x = xv.x + beta * r.x + (1.f - beta) * o.x;
  y.y = xv.y + beta * r.y + (1.f - beta) * o.y;
  float sm = y.x + y.y;
#pragma unroll
  for (int mm = 32; mm >= 1; mm >>= 1) sm += __shfl_xor(sm, mm);
  float mean = sm * (1.f / 128.f);
  float dx = y.x - mean, dy = y.y - mean;
  float vs = dx * dx + dy * dy;
#pragma unroll
  for (int mm = 32; mm >= 1; mm >>= 1) vs += __shfl_xor(vs, mm);
  float rstd = rsqrtf(vs * (1.f / 128.f) + 1e-5f);
  *(float2*)(x1 + base) = make_float2(dx * rstd, dy * rstd);
}

// ---------------- out = LN(a + b); one wave per row ----------------
__global__ void ln_add(const float* __restrict__ a, const float* __restrict__ b,
                       float* __restrict__ out, int R)
{
  int wid = threadIdx.x >> 6, lane = threadIdx.x & 63;
  int r = blockIdx.x * 4 + wid;
  if (r >= R) return;
  size_t base = (size_t)r * 128 + lane * 2;
  float2 av = *(const float2*)(a + base);
  float2 bv = *(const float2*)(b + base);
  float2 y = make_float2(av.x + bv.x, av.y + bv.y);
  float sm = y.x + y.y;
#pragma unroll
  for (int mm = 32; mm >= 1; mm >>= 1) sm += __shfl_xor(sm, mm);
  float mean = sm * (1.f / 128.f);
  float dx = y.x - mean, dy = y.y - mean;
  float vs = dx * dx + dy * dy;
#pragma unroll
  for (int mm = 32; mm >= 1; mm >>= 1) vs += __shfl_xor(vs, mm);
  float rstd = rsqrtf(vs * (1.f / 128.f) + 1e-5f);
  *(float2*)(out + base) = make_float2(dx * rstd, dy * rstd);
}

// ---------------- global tokens attend over nodes: one wave per (b,g,h) ----------------
__global__ void glob_attn(const float* __restrict__ Qg, const float* __restrict__ Kall,
                          const float* __restrict__ Vall, float* __restrict__ Og,
                          float* __restrict__ m_gl, float* __restrict__ is_gl, int MAXN)
{
  int blk = blockIdx.x;                 // b*64 + g*8 + h
  int h = blk & 7, g = (blk >> 3) & 7, b = blk >> 6;
  int lane = threadIdx.x;
  const float4* q4 = (const float4*)(Qg + (size_t)(b * NGT + g) * 128 + h * 16);
  float4 q0 = q4[0], q1 = q4[1], q2 = q4[2], q3 = q4[3];
  float m = -3.0e38f, s = 0.f;
  float4 a0 = make_float4(0, 0, 0, 0), a1 = a0, a2 = a0, a3 = a0;
  for (int n = lane; n < MAXN; n += 64) {
    size_t base = ((size_t)(b * MAXN + n)) * 128 + h * 16;
    const float4* k4 = (const float4*)(Kall + base);
    float d = dot4(q0, k4[0]) + dot4(q1, k4[1]) + dot4(q2, k4[2]) + dot4(q3, k4[3]);
    d *= 0.25f;
    float mn = fmaxf(m, d);
    float sc = expf(m - mn);
    float p = expf(d - mn);
    const float4* v4 = (const float4*)(Vall + base);
    a0 = scale_madd(a0, sc, v4[0], p);
    a1 = scale_madd(a1, sc, v4[1], p);
    a2 = scale_madd(a2, sc, v4[2], p);
    a3 = scale_madd(a3, sc, v4[3], p);
    s = s * sc + p;
    m = mn;
  }
#pragma unroll
  for (int off = 32; off >= 1; off >>= 1) {
    float m2 = __shfl_xor(m, off);
    float s2 = __shfl_xor(s, off);
    float4 c0 = shfl_xor4(a0, off), c1 = shfl_xor4(a1, off);
    float4 c2 = shfl_xor4(a2, off), c3 = shfl_xor4(a3, off);
    float mn = fmaxf(m, m2);
    float e1 = expf(m - mn), e2 = expf(m2 - mn);
    s = s * e1 + s2 * e2;
    a0 = comb4(a0, e1, c0, e2);
    a1 = comb4(a1, e1, c1, e2);
    a2 = comb4(a2, e1, c2, e2);
    a3 = comb4(a3, e1, c3, e2);
    m = mn;
  }
  if (lane == 0) {
    float inv = 1.f / s;
    float4* o4 = (float4*)(Og + (size_t)(b * NGT + g) * 128 + h * 16);
    o4[0] = make_float4(a0.x * inv, a0.y * inv, a0.z * inv, a0.w * inv);
    o4[1] = make_float4(a1.x * inv, a1.y * inv, a1.z * inv, a1.w * inv);
    o4[2] = make_float4(a2.x * inv, a2.y * inv, a2.z * inv, a2.w * inv);
    o4[3] = make_float4(a3.x * inv, a3.y * inv, a3.z * inv, a3.w * inv);
    m_gl[blk] = m;
    is_gl[blk] = inv;
  }
}

// ---------------- P rows (head-mean attention for the 4 "local" global tokens) ----------------
__global__ void pker(const float* __restrict__ Qg, const float* __restrict__ Kall,
                     const float* __restrict__ m_gl, const float* __restrict__ is_gl,
                     float* __restrict__ P, int MAXN)
{
  int nchunk = (MAXN + 255) >> 8;
  int b = blockIdx.x / nchunk;
  int ch = blockIdx.x % nchunk;
  __shared__ float qs[4 * 128];
  __shared__ float ms[32], iss[32];
  for (int i = threadIdx.x; i < 512; i += 256)
    qs[i] = Qg[(size_t)(b * NGT + LSTOK) * 128 + i];
  if (threadIdx.x < 32) {
    int g = threadIdx.x >> 3, h = threadIdx.x & 7;
    ms[threadIdx.x]  = m_gl[(b * NGT + LSTOK + g) * H + h];
    iss[threadIdx.x] = is_gl[(b * NGT + LSTOK + g) * H + h];
  }
  __syncthreads();
  int n = ch * 256 + threadIdx.x;
  if (n >= MAXN) return;
  float acc[4] = {0.f, 0.f, 0.f, 0.f};
  size_t kbase = ((size_t)(b * MAXN + n)) * 128;
  for (int h = 0; h < H; h++) {
    const float4* k4 = (const float4*)(Kall + kbase + h * 16);
    float4 k0 = k4[0], k1 = k4[1], k2 = k4[2], k3 = k4[3];
#pragma unroll
    for (int g = 0; g < 4; g++) {
      const float4* qp = (const float4*)(qs + g * 128 + h * 16);
      float d = dot4(k0, qp[0]) + dot4(k1, qp[1]) + dot4(k2, qp[2]) + dot4(k3, qp[3]);
      d *= 0.25f;
      acc[g] += expf(d - ms[g * 8 + h]) * iss[g * 8 + h];
    }
  }
#pragma unroll
  for (int g = 0; g < 4; g++)
    P[(size_t)(b * 4 + g) * MAXN + n] = acc[g] * 0.125f;
}

// ---------------- reg: off-diagonal Gram of row-normalized P ----------------
__global__ void regk(const float* __restrict__ P, float* __restrict__ offb, int MAXN)
{
  int b = blockIdx.x;
  int t = threadIdx.x;
  float v[10];
#pragma unroll
  for (int i = 0; i < 10; i++) v[i] = 0.f;
  for (int n = t; n < MAXN; n += 256) {
    float p0 = P[(size_t)(b * 4 + 0) * MAXN + n];
    float p1 = P[(size_t)(b * 4 + 1) * MAXN + n];
    float p2 = P[(size_t)(b * 4 + 2) * MAXN + n];
    float p3 = P[(size_t)(b * 4 + 3) * MAXN + n];
    v[0] += p0; v[1] += p1; v[2] += p2; v[3] += p3;
    v[4] += p0 * p1; v[5] += p0 * p2; v[6] += p0 * p3;
    v[7] += p1 * p2; v[8] += p1 * p3; v[9] += p2 * p3;
  }
#pragma unroll
  for (int i = 0; i < 10; i++) {
    float x = v[i];
#pragma unroll
    for (int mm = 32; mm >= 1; mm >>= 1) x += __shfl_xor(x, mm);
    v[i] = x;
  }
  __shared__ float red[4][10];
  int wid = t >> 6, lane = t & 63;
  if (lane == 0)
    for (int i = 0; i < 10; i++) red[wid][i] = v[i];
  __syncthreads();
  if (t == 0) {
    float r[10];
    for (int i = 0; i < 10; i++) r[i] = red[0][i] + red[1][i] + red[2][i] + red[3][i];
    float r0 = r[0] + 1e-8f, r1 = r[1] + 1e-8f, r2 = r[2] + 1e-8f, r3 = r[3] + 1e-8f;
    float off = 2.f * (r[4] / (r0 * r1) + r[5] / (r0 * r2) + r[6] / (r0 * r3)
                     + r[7] / (r1 * r2) + r[8] / (r1 * r3) + r[9] / (r2 * r3));
    offb[b] = off * (1.f / 12.f);   // (Kt*Kt - Kt) = 12
  }
}

__global__ void regfin(const float* __restrict__ offb, float* __restrict__ out) {
  if (threadIdx.x == 0 && blockIdx.x == 0) {
    float s = 0.f;
    for (int i = 0; i < 8; i++) s += offb[i];
    *out = s * (1.f / 8.f);
  }
}

// ---------------- nodes attend to 8 global tokens: one thread per (node, head) ----------------
__global__ void node_attn(const float* __restrict__ Qn, const float* __restrict__ Kg,
                          const float* __restrict__ Vg, float* __restrict__ On,
                          int N, int MAXN)
{
  int gid = blockIdx.x * 256 + threadIdx.x;
  if (gid >= N * H) return;
  int n = gid >> 3, h = gid & 7;
  int b = n / MAXN;
  const float4* q4 = (const float4*)(Qn + (size_t)n * 128 + h * 16);
  float4 q0 = q4[0], q1 = q4[1], q2 = q4[2], q3 = q4[3];
  float l[NGT];
  float mx = -3.0e38f;
#pragma unroll
  for (int tk = 0; tk < NGT; tk++) {
    const float4* k4 = (const float4*)(Kg + (size_t)(b * NGT + tk) * 128 + h * 16);
    float d = dot4(q0, k4[0]) + dot4(q1, k4[1]) + dot4(q2, k4[2]) + dot4(q3, k4[3]);
    l[tk] = d * 0.25f;
    mx = fmaxf(mx, l[tk]);
  }
  float s = 0.f;
#pragma unroll
  for (int tk = 0; tk < NGT; tk++) { l[tk] = expf(l[tk] - mx); s += l[tk]; }
  float inv = 1.f / s;
  float4 a0 = make_float4(0, 0, 0, 0), a1 = a0, a2 = a0, a3 = a0;
#pragma unroll
  for (int tk = 0; tk < NGT; tk++) {
    float p = l[tk] * inv;
    const float4* v4 = (const float4*)(Vg + (size_t)(b * NGT + tk) * 128 + h * 16);
    a0 = scale_madd(a0, 1.f, v4[0], p);
    a1 = scale_madd(a1, 1.f, v4[1], p);
    a2 = scale_madd(a2, 1.f, v4[2], p);
    a3 = scale_madd(a3, 1.f, v4[3], p);
  }
  float4* o4 = (float4*)(On + (size_t)n * 128 + h * 16);
  o4[0] = a0; o4[1] = a1; o4[2] = a2; o4[3] = a3;
}

extern "C" void kernel_launch(void* const* d_in, const int* in_sizes, int n_in,
                              void* d_out, int out_size, void* d_ws, size_t ws_size,
                              hipStream_t stream)
{
  const float* x     = (const float*)d_in[0];
  const int*   ei    = (const int*)d_in[1];
  const float* gh    = (const float*)d_in[2];
  // d_in[3] batch (unused by reference), d_in[4]/d_in[5] token counts (fixed 4/4)
  const float* Wq    = (const float*)d_in[6];
  const float* bqv   = (const float*)d_in[7];
  const float* Wk    = (const float*)d_in[8];
  const float* bkv   = (const float*)d_in[9];
  const float* Wv    = (const float*)d_in[10];
  const float* bvv   = (const float*)d_in[11];
  const float* Wsk   = (const float*)d_in[12];
  const float* bsk   = (const float*)d_in[13];
  const float* Wbeta = (const float*)d_in[14];
  const float* ngw   = (const float*)d_in[15];
  const float* ngb   = (const float*)d_in[16];
  const float* ngow  = (const float*)d_in[17];
  const float* ngob  = (const float*)d_in[18];
  const float* gnw   = (const float*)d_in[19];
  const float* gnb   = (const float*)d_in[20];
  const float* gnow  = (const float*)d_in[21];
  const float* gnob  = (const float*)d_in[22];
  const float* W1    = (const float*)d_in[23];
  const float* b1v   = (const float*)d_in[24];
  const float* W2    = (const float*)d_in[25];
  const float* b2v   = (const float*)d_in[26];

  const int N    = in_sizes[0] / D;   // 50000
  const int E    = in_sizes[1] / 2;   // 400000
  const int Bb   = 8;
  const int MAXN = N / Bb;            // 6250

  const int* srcI = ei;
  const int* dstI = ei + E;

  size_t ND = (size_t)N * D;
  float* fw = (float*)d_ws;
  // 5 N*D float buffers with staged reuse:
  float* w0 = fw;            // q_all -> x1
  float* w1 = fw + ND;       // k_all -> K_all(glob) -> x2
  float* w2 = fw + 2 * ND;   // v_all -> V_all(glob) -> O_nodes -> ff[0:ND]
  float* w3 = fw + 3 * ND;   // xr -> proj tmp -> ff[ND:2ND]
  float* w4 = fw + 4 * ND;   // attn_out -> Qn -> ff2
  float* misc = fw + 5 * ND;
  float* Qg    = misc;               // 64*128
  float* Og    = Qg + 8192;
  float* gout  = Og + 8192;
  float* Kg    = gout + 8192;
  float* Vg    = Kg + 8192;
  float* m_gl  = Vg + 8192;          // 512
  float* is_gl = m_gl + 512;         // 512
  float* Pbuf  = is_gl + 512;        // 8*4*MAXN
  float* offb  = Pbuf + (size_t)Bb * 4 * MAXN;   // 8
  int* deg       = (int*)(offb + 16);
  int* row_start = deg + N;          // N+1
  int* cursor    = row_start + N + 1;
  int* edge_list = cursor + N;       // E

  float* outx   = (float*)d_out;
  float* outgh  = outx + ND;                       // 8192
  float* outreg = outgh + (size_t)Bb * NGT * D;    // 1

  const int GX = (N + 63) / 64;
  dim3 blk256(256);

  // CSR build (edge list grouped by dst)
  hipMemsetAsync(deg, 0, (size_t)N * sizeof(int), stream);
  count_deg<<<dim3((E + 255) / 256), blk256, 0, stream>>>(dstI, deg, E);
  scan_kernel<<<dim3(1), dim3(1024), 0, stream>>>(deg, row_start, cursor, N, E);
  fill_edges<<<dim3((E + 255) / 256), blk256, 0, stream>>>(dstI, cursor, edge_list, E);

  // tconv projections
  gemm_nt<128><<<dim3(GX, 1), blk256, 0, stream>>>(x, Wq, bqv, w0, N, D, 0);
  gemm_nt<128><<<dim3(GX, 1), blk256, 0, stream>>>(x, Wk, bkv, w1, N, D, 0);
  gemm_nt<128><<<dim3(GX, 1), blk256, 0, stream>>>(x, Wv, bvv, w2, N, D, 0);
  gemm_nt<128><<<dim3(GX, 1), blk256, 0, stream>>>(x, Wsk, bsk, w3, N, D, 0);

  // edge attention + gate + LN  -> x1 in w0
  tconv_attn<<<dim3((N * H + 255) / 256), blk256, 0, stream>>>(w0, w1, w2, row_start, edge_list, srcI, w4, N);
  gate_ln<<<dim3((N + 3) / 4), blk256, 0, stream>>>(x, w4, w3, Wbeta, w0, N);

  // global MHA (tokens attend over nodes)
  gemm_nt<128><<<dim3(GX, 1), blk256, 0, stream>>>(w0, ngw + 128 * 128, ngb + 128, w1, N, D, 0); // K_all
  gemm_nt<128><<<dim3(GX, 1), blk256, 0, stream>>>(w0, ngw + 256 * 128, ngb + 256, w2, N, D, 0); // V_all
  gemm_small<<<dim3(64), dim3(128), 0, stream>>>(gh, ngw, ngb, Qg, 64);
  glob_attn<<<dim3(512), dim3(64), 0, stream>>>(Qg, w1, w2, Og, m_gl, is_gl, MAXN);
  pker<<<dim3(8 * ((MAXN + 255) / 256)), blk256, 0, stream>>>(Qg, w1, m_gl, is_gl, Pbuf, MAXN);
  regk<<<dim3(8), blk256, 0, stream>>>(Pbuf, offb, MAXN);
  regfin<<<dim3(1), dim3(64), 0, stream>>>(offb, outreg);

  gemm_small<<<dim3(64), dim3(128), 0, stream>>>(Og, ngow, ngob, gout, 64);
  ln_add<<<dim3(16), blk256, 0, stream>>>(gh, gout, outgh, 64);   // new global_h -> d_out

  // nodes attend to global tokens
  gemm_small<<<dim3(64), dim3(128), 0, stream>>>(outgh, gnw + 128 * 128, gnb + 128, Kg, 64);
  gemm_small<<<dim3(64), dim3(128), 0, stream>>>(outgh, gnw + 256 * 128, gnb + 256, Vg, 64);
  gemm_nt<128><<<dim3(GX, 1), blk256, 0, stream>>>(w0, gnw, gnb, w4, N, D, 0);  // Qn
  node_attn<<<dim3((N * H + 255) / 256), blk256, 0, stream>>>(w4, Kg, Vg, w2, N, MAXN);
  gemm_nt<128><<<dim3(GX, 1), blk256, 0, stream>>>(w2, gnow, gnob, w3, N, D, 0); // out proj
  ln_add<<<dim3((N + 3) / 4), blk256, 0, stream>>>(w0, w3, w1, N);               // x2

  // FF + final LN -> d_out x
  gemm_nt<128><<<dim3(GX, 2), blk256, 0, stream>>>(w1, W1, b1v, w2, N, 2 * D, 1);  // relu(x2@W1.T+b1), N x 256
  gemm_nt<256><<<dim3(GX, 1), blk256, 0, stream>>>(w2, W2, b2v, w4, N, D, 0);
  ln_add<<<dim3((N + 3) / 4), blk256, 0, stream>>>(w1, w4, outx, N);
}

// Round 2
// 619.180 us; speedup vs baseline: 1.9042x; 1.9042x over previous
//
#include <hip/hip_runtime.h>
#include <math.h>

#define D 128
#define H 8
#define NGT 8
#define LSTOK 4   // n_global_tokens_global (fixed by problem)

typedef short bf16x8 __attribute__((ext_vector_type(8)));
typedef float f32x4  __attribute__((ext_vector_type(4)));

__device__ __forceinline__ short f2bf(float f) {
  union { float f; unsigned u; } v; v.f = f;
  unsigned r = v.u + 0x7FFFu + ((v.u >> 16) & 1u);   // RNE
  return (short)(r >> 16);
}

__device__ __forceinline__ float dot4(float4 a, float4 b) {
  return a.x*b.x + a.y*b.y + a.z*b.z + a.w*b.w;
}
__device__ __forceinline__ float4 scale_madd(float4 a, float sc, float4 v, float p) {
  return make_float4(fmaf(p, v.x, a.x*sc), fmaf(p, v.y, a.y*sc),
                     fmaf(p, v.z, a.z*sc), fmaf(p, v.w, a.w*sc));
}
__device__ __forceinline__ float4 comb4(float4 a, float e1, float4 c, float e2) {
  return make_float4(a.x*e1 + c.x*e2, a.y*e1 + c.y*e2, a.z*e1 + c.z*e2, a.w*e1 + c.w*e2);
}
__device__ __forceinline__ float4 shfl_xor4(float4 v, int off) {
  return make_float4(__shfl_xor(v.x, off), __shfl_xor(v.y, off),
                     __shfl_xor(v.z, off), __shfl_xor(v.w, off));
}

// ---------------- weight fp32 -> bf16 conversion (one-shot, 10 matrices) ----------------
struct CvtArgs {
  const float* s[10];
  short*       d[10];
  int          n[10];
};

__global__ void cvt_weights(CvtArgs a) {
  int which = blockIdx.y;
  const float* s = a.s[which];
  short* d = a.d[which];
  int n = a.n[which];
  int i = (blockIdx.x * 256 + threadIdx.x) * 4;
  if (i + 3 < n) {
    float4 v = *(const float4*)(s + i);
    d[i]     = f2bf(v.x);
    d[i + 1] = f2bf(v.y);
    d[i + 2] = f2bf(v.z);
    d[i + 3] = f2bf(v.w);
  }
}

// ---------------- MFMA bf16 GEMM: out[r][c] = sum_k A[r][k] * W[c][k] + bias[c] ----------------
// A fp32 row-major [Nrows][K]; Wb bf16 row-major [Ccols][K]; out fp32 [Nrows][Ccols].
// Block: 256 threads (4 waves), 128x128 output tile; each wave a 64x64 quadrant.
// K staged in 128-chunks; LDS rows padded to 136 shorts (bank-spread).
__global__ void __launch_bounds__(256) gemm_mfma(const float* __restrict__ A,
    const short* __restrict__ Wb, const float* __restrict__ bias,
    float* __restrict__ out, int Nrows, int K, int Ccols, int relu)
{
  __shared__ short As[128 * 136];
  __shared__ short Ws[128 * 136];
  const int t = threadIdx.x;
  const int rowBase = blockIdx.x * 128;
  const int colBase = blockIdx.y * 128;
  const int wid = t >> 6, lane = t & 63;
  const int wr = wid >> 1, wc = wid & 1;

  f32x4 acc[4][4];
  f32x4 z4 = {0.f, 0.f, 0.f, 0.f};
#pragma unroll
  for (int m = 0; m < 4; m++)
#pragma unroll
    for (int n = 0; n < 4; n++) acc[m][n] = z4;

  for (int kout = 0; kout < K; kout += 128) {
    // stage W chunk (straight bf16 copy)
#pragma unroll
    for (int it = 0; it < 8; ++it) {
      int chunk = it * 256 + t;          // 0..2047 chunks of 8 shorts
      int r = chunk >> 4, c8 = (chunk & 15) * 8;
      *(bf16x8*)(Ws + r * 136 + c8) =
          *(const bf16x8*)(Wb + (size_t)(colBase + r) * K + kout + c8);
    }
    // stage A chunk (fp32 -> bf16)
#pragma unroll
    for (int it = 0; it < 8; ++it) {
      int chunk = it * 256 + t;
      int r = chunk >> 4, c8 = (chunk & 15) * 8;
      int gr = rowBase + r;
      bf16x8 v8 = {0, 0, 0, 0, 0, 0, 0, 0};
      if (gr < Nrows) {
        const float* ap = A + (size_t)gr * K + kout + c8;
        float4 f0 = *(const float4*)(ap);
        float4 f1 = *(const float4*)(ap + 4);
        v8[0] = f2bf(f0.x); v8[1] = f2bf(f0.y); v8[2] = f2bf(f0.z); v8[3] = f2bf(f0.w);
        v8[4] = f2bf(f1.x); v8[5] = f2bf(f1.y); v8[6] = f2bf(f1.z); v8[7] = f2bf(f1.w);
      }
      *(bf16x8*)(As + r * 136 + c8) = v8;
    }
    __syncthreads();

    const int lrow = lane & 15;
    const int lk = (lane >> 4) * 8;
#pragma unroll
    for (int kk = 0; kk < 4; ++kk) {
      int kb = kk * 32 + lk;
      bf16x8 af[4], bfr[4];
#pragma unroll
      for (int m = 0; m < 4; ++m)
        af[m] = *(const bf16x8*)(As + (wr * 64 + m * 16 + lrow) * 136 + kb);
#pragma unroll
      for (int n = 0; n < 4; ++n)
        bfr[n] = *(const bf16x8*)(Ws + (wc * 64 + n * 16 + lrow) * 136 + kb);
#pragma unroll
      for (int m = 0; m < 4; ++m)
#pragma unroll
        for (int n = 0; n < 4; ++n)
          acc[m][n] = __builtin_amdgcn_mfma_f32_16x16x32_bf16(af[m], bfr[n], acc[m][n], 0, 0, 0);
    }
    __syncthreads();
  }

  // epilogue: C/D layout col = lane&15, row = (lane>>4)*4 + reg
  const int ccol = lane & 15;
  const int rquad = (lane >> 4) * 4;
#pragma unroll
  for (int n = 0; n < 4; ++n) {
    int col = colBase + wc * 64 + n * 16 + ccol;
    float bb = bias[col];
#pragma unroll
    for (int m = 0; m < 4; ++m) {
      int row0 = rowBase + wr * 64 + m * 16 + rquad;
#pragma unroll
      for (int r = 0; r < 4; ++r) {
        int gr = row0 + r;
        if (gr < Nrows) {
          float v = acc[m][n][r] + bb;
          if (relu) v = fmaxf(v, 0.f);
          out[(size_t)gr * Ccols + col] = v;
        }
      }
    }
  }
}

// small GEMM (M rows <= 64, K=C=128): one block per row
__global__ void gemm_small(const float* __restrict__ A, const float* __restrict__ W,
                           const float* __restrict__ bias, float* __restrict__ out, int M)
{
  int r = blockIdx.x;
  int c = threadIdx.x;
  __shared__ float as[128];
  as[c] = A[(size_t)r * 128 + c];
  __syncthreads();
  float acc = bias[c];
  const float* wr = W + (size_t)c * 128;
#pragma unroll 4
  for (int k = 0; k < 128; k++) acc += as[k] * wr[k];
  out[(size_t)r * 128 + c] = acc;
}

// ---------------- CSR build ----------------
__global__ void count_deg(const int* __restrict__ dst, int* __restrict__ deg, int E) {
  int e = blockIdx.x * 256 + threadIdx.x;
  if (e < E) atomicAdd(&deg[dst[e]], 1);
}

__global__ void scan_kernel(const int* __restrict__ deg, int* __restrict__ row_start,
                            int* __restrict__ cursor, int N, int E)
{
  __shared__ int sh[1024];
  int t = threadIdx.x;
  int chunk = (N + 1023) >> 10;
  int b0 = t * chunk;
  int b1 = b0 + chunk; if (b1 > N) b1 = N;
  int s = 0;
  for (int i = b0; i < b1 && i < N; i++) s += deg[i];
  sh[t] = s;
  __syncthreads();
  for (int off = 1; off < 1024; off <<= 1) {
    int v = (t >= off) ? sh[t - off] : 0;
    __syncthreads();
    sh[t] += v;
    __syncthreads();
  }
  int base = (t == 0) ? 0 : sh[t - 1];
  for (int i = b0; i < b1 && i < N; i++) {
    row_start[i] = base; cursor[i] = base; base += deg[i];
  }
  if (t == 1023) row_start[N] = E;
}

__global__ void fill_edges(const int* __restrict__ dst, int* __restrict__ cursor,
                           int* __restrict__ edge_list, int E) {
  int e = blockIdx.x * 256 + threadIdx.x;
  if (e < E) {
    int p = atomicAdd(&cursor[dst[e]], 1);
    edge_list[p] = e;
  }
}

// ---------------- tconv edge attention: one thread per (node, head), online softmax ----------------
__global__ void tconv_attn(const float* __restrict__ q_all, const float* __restrict__ k_all,
                           const float* __restrict__ v_all, const int* __restrict__ row_start,
                           const int* __restrict__ edge_list, const int* __restrict__ srcI,
                           float* __restrict__ out, int N)
{
  int gid = blockIdx.x * 256 + threadIdx.x;
  if (gid >= N * H) return;
  int n = gid >> 3, h = gid & 7;
  size_t qb = (size_t)n * 128 + h * 16;
  const float4* q4 = (const float4*)(q_all + qb);
  float4 q0 = q4[0], q1 = q4[1], q2 = q4[2], q3 = q4[3];
  float m = -3.0e38f, s = 0.f;
  float4 a0 = make_float4(0, 0, 0, 0), a1 = a0, a2 = a0, a3 = a0;
  int e1 = row_start[n + 1];
  for (int ei = row_start[n]; ei < e1; ei++) {
    int sn = srcI[edge_list[ei]];
    size_t kb = (size_t)sn * 128 + h * 16;
    const float4* k4 = (const float4*)(k_all + kb);
    float d = dot4(q0, k4[0]) + dot4(q1, k4[1]) + dot4(q2, k4[2]) + dot4(q3, k4[3]);
    d *= 0.25f;
    float mn = fmaxf(m, d);
    float sc = expf(m - mn);
    float p = expf(d - mn);
    const float4* v4 = (const float4*)(v_all + kb);
    a0 = scale_madd(a0, sc, v4[0], p);
    a1 = scale_madd(a1, sc, v4[1], p);
    a2 = scale_madd(a2, sc, v4[2], p);
    a3 = scale_madd(a3, sc, v4[3], p);
    s = s * sc + p;
    m = mn;
  }
  float inv = 1.f / (s + 1e-16f);
  float4* o4 = (float4*)(out + qb);
  o4[0] = make_float4(a0.x * inv, a0.y * inv, a0.z * inv, a0.w * inv);
  o4[1] = make_float4(a1.x * inv, a1.y * inv, a1.z * inv, a1.w * inv);
  o4[2] = make_float4(a2.x * inv, a2.y * inv, a2.z * inv, a2.w * inv);
  o4[3] = make_float4(a3.x * inv, a3.y * inv, a3.z * inv, a3.w * inv);
}

// ---------------- gate (sigmoid beta) + residual + LN; one wave per node ----------------
__global__ void gate_ln(const float* __restrict__ x, const float* __restrict__ att,
                        const float* __restrict__ xr, const float* __restrict__ Wb,
                        float* __restrict__ x1, int N)
{
  int wid = threadIdx.x >> 6, lane = threadIdx.x & 63;
  int n = blockIdx.x * 4 + wid;
  if (n >= N) return;
  size_t base = (size_t)n * 128 + lane * 2;
  float2 o = *(const float2*)(att + base);
  float2 r = *(const float2*)(xr + base);
  float2 xv = *(const float2*)(x + base);
  float2 w0 = *(const float2*)(Wb + lane * 2);
  float2 w1 = *(const float2*)(Wb + 128 + lane * 2);
  float2 w2 = *(const float2*)(Wb + 256 + lane * 2);
  float ts = o.x * w0.x + o.y * w0.y + r.x * w1.x + r.y * w1.y
           + (o.x - r.x) * w2.x + (o.y - r.y) * w2.y;
#pragma unroll
  for (int mm = 32; mm >= 1; mm >>= 1) ts += __shfl_xor(ts, mm);
  float beta = 1.f / (1.f + expf(-ts));
  float2 y;
  y.x = xv.x + beta * r.x + (1.f - beta) * o.x;
  y.y = xv.y + beta * r.y + (1.f - beta) * o.y;
  float sm = y.x + y.y;
#pragma unroll
  for (int mm = 32; mm >= 1; mm >>= 1) sm += __shfl_xor(sm, mm);
  float mean = sm * (1.f / 128.f);
  float dx = y.x - mean, dy = y.y - mean;
  float vs = dx * dx + dy * dy;
#pragma unroll
  for (int mm = 32; mm >= 1; mm >>= 1) vs += __shfl_xor(vs, mm);
  float rstd = rsqrtf(vs * (1.f / 128.f) + 1e-5f);
  *(float2*)(x1 + base) = make_float2(dx * rstd, dy * rstd);
}

// ---------------- out = LN(a + b); one wave per row ----------------
__global__ void ln_add(const float* __restrict__ a, const float* __restrict__ b,
                       float* __restrict__ out, int R)
{
  int wid = threadIdx.x >> 6, lane = threadIdx.x & 63;
  int r = blockIdx.x * 4 + wid;
  if (r >= R) return;
  size_t base = (size_t)r * 128 + lane * 2;
  float2 av = *(const float2*)(a + base);
  float2 bv = *(const float2*)(b + base);
  float2 y = make_float2(av.x + bv.x, av.y + bv.y);
  float sm = y.x + y.y;
#pragma unroll
  for (int mm = 32; mm >= 1; mm >>= 1) sm += __shfl_xor(sm, mm);
  float mean = sm * (1.f / 128.f);
  float dx = y.x - mean, dy = y.y - mean;
  float vs = dx * dx + dy * dy;
#pragma unroll
  for (int mm = 32; mm >= 1; mm >>= 1) vs += __shfl_xor(vs, mm);
  float rstd = rsqrtf(vs * (1.f / 128.f) + 1e-5f);
  *(float2*)(out + base) = make_float2(dx * rstd, dy * rstd);
}

// ---------------- global tokens attend over nodes: one wave per (b,g,h) ----------------
__global__ void glob_attn(const float* __restrict__ Qg, const float* __restrict__ Kall,
                          const float* __restrict__ Vall, float* __restrict__ Og,
                          float* __restrict__ m_gl, float* __restrict__ is_gl, int MAXN)
{
  int blk = blockIdx.x;                 // b*64 + g*8 + h
  int h = blk & 7, g = (blk >> 3) & 7, b = blk >> 6;
  int lane = threadIdx.x;
  const float4* q4 = (const float4*)(Qg + (size_t)(b * NGT + g) * 128 + h * 16);
  float4 q0 = q4[0], q1 = q4[1], q2 = q4[2], q3 = q4[3];
  float m = -3.0e38f, s = 0.f;
  float4 a0 = make_float4(0, 0, 0, 0), a1 = a0, a2 = a0, a3 = a0;
  for (int n = lane; n < MAXN; n += 64) {
    size_t base = ((size_t)(b * MAXN + n)) * 128 + h * 16;
    const float4* k4 = (const float4*)(Kall + base);
    float d = dot4(q0, k4[0]) + dot4(q1, k4[1]) + dot4(q2, k4[2]) + dot4(q3, k4[3]);
    d *= 0.25f;
    float mn = fmaxf(m, d);
    float sc = expf(m - mn);
    float p = expf(d - mn);
    const float4* v4 = (const float4*)(Vall + base);
    a0 = scale_madd(a0, sc, v4[0], p);
    a1 = scale_madd(a1, sc, v4[1], p);
    a2 = scale_madd(a2, sc, v4[2], p);
    a3 = scale_madd(a3, sc, v4[3], p);
    s = s * sc + p;
    m = mn;
  }
#pragma unroll
  for (int off = 32; off >= 1; off >>= 1) {
    float m2 = __shfl_xor(m, off);
    float s2 = __shfl_xor(s, off);
    float4 c0 = shfl_xor4(a0, off), c1 = shfl_xor4(a1, off);
    float4 c2 = shfl_xor4(a2, off), c3 = shfl_xor4(a3, off);
    float mn = fmaxf(m, m2);
    float e1 = expf(m - mn), e2 = expf(m2 - mn);
    s = s * e1 + s2 * e2;
    a0 = comb4(a0, e1, c0, e2);
    a1 = comb4(a1, e1, c1, e2);
    a2 = comb4(a2, e1, c2, e2);
    a3 = comb4(a3, e1, c3, e2);
    m = mn;
  }
  if (lane == 0) {
    float inv = 1.f / s;
    float4* o4 = (float4*)(Og + (size_t)(b * NGT + g) * 128 + h * 16);
    o4[0] = make_float4(a0.x * inv, a0.y * inv, a0.z * inv, a0.w * inv);
    o4[1] = make_float4(a1.x * inv, a1.y * inv, a1.z * inv, a1.w * inv);
    o4[2] = make_float4(a2.x * inv, a2.y * inv, a2.z * inv, a2.w * inv);
    o4[3] = make_float4(a3.x * inv, a3.y * inv, a3.z * inv, a3.w * inv);
    m_gl[blk] = m;
    is_gl[blk] = inv;
  }
}

// ---------------- P rows (head-mean attention for the 4 "local" global tokens) ----------------
__global__ void pker(const float* __restrict__ Qg, const float* __restrict__ Kall,
                     const float* __restrict__ m_gl, const float* __restrict__ is_gl,
                     float* __restrict__ P, int MAXN)
{
  int nchunk = (MAXN + 255) >> 8;
  int b = blockIdx.x / nchunk;
  int ch = blockIdx.x % nchunk;
  __shared__ float qs[4 * 128];
  __shared__ float ms[32], iss[32];
  for (int i = threadIdx.x; i < 512; i += 256)
    qs[i] = Qg[(size_t)(b * NGT + LSTOK) * 128 + i];
  if (threadIdx.x < 32) {
    int g = threadIdx.x >> 3, h = threadIdx.x & 7;
    ms[threadIdx.x]  = m_gl[(b * NGT + LSTOK + g) * H + h];
    iss[threadIdx.x] = is_gl[(b * NGT + LSTOK + g) * H + h];
  }
  __syncthreads();
  int n = ch * 256 + threadIdx.x;
  if (n >= MAXN) return;
  float acc[4] = {0.f, 0.f, 0.f, 0.f};
  size_t kbase = ((size_t)(b * MAXN + n)) * 128;
  for (int h = 0; h < H; h++) {
    const float4* k4 = (const float4*)(Kall + kbase + h * 16);
    float4 k0 = k4[0], k1 = k4[1], k2 = k4[2], k3 = k4[3];
#pragma unroll
    for (int g = 0; g < 4; g++) {
      const float4* qp = (const float4*)(qs + g * 128 + h * 16);
      float d = dot4(k0, qp[0]) + dot4(k1, qp[1]) + dot4(k2, qp[2]) + dot4(k3, qp[3]);
      d *= 0.25f;
      acc[g] += expf(d - ms[g * 8 + h]) * iss[g * 8 + h];
    }
  }
#pragma unroll
  for (int g = 0; g < 4; g++)
    P[(size_t)(b * 4 + g) * MAXN + n] = acc[g] * 0.125f;
}

// ---------------- reg: off-diagonal Gram of row-normalized P ----------------
__global__ void regk(const float* __restrict__ P, float* __restrict__ offb, int MAXN)
{
  int b = blockIdx.x;
  int t = threadIdx.x;
  float v[10];
#pragma unroll
  for (int i = 0; i < 10; i++) v[i] = 0.f;
  for (int n = t; n < MAXN; n += 256) {
    float p0 = P[(size_t)(b * 4 + 0) * MAXN + n];
    float p1 = P[(size_t)(b * 4 + 1) * MAXN + n];
    float p2 = P[(size_t)(b * 4 + 2) * MAXN + n];
    float p3 = P[(size_t)(b * 4 + 3) * MAXN + n];
    v[0] += p0; v[1] += p1; v[2] += p2; v[3] += p3;
    v[4] += p0 * p1; v[5] += p0 * p2; v[6] += p0 * p3;
    v[7] += p1 * p2; v[8] += p1 * p3; v[9] += p2 * p3;
  }
#pragma unroll
  for (int i = 0; i < 10; i++) {
    float x = v[i];
#pragma unroll
    for (int mm = 32; mm >= 1; mm >>= 1) x += __shfl_xor(x, mm);
    v[i] = x;
  }
  __shared__ float red[4][10];
  int wid = t >> 6, lane = t & 63;
  if (lane == 0)
    for (int i = 0; i < 10; i++) red[wid][i] = v[i];
  __syncthreads();
  if (t == 0) {
    float r[10];
    for (int i = 0; i < 10; i++) r[i] = red[0][i] + red[1][i] + red[2][i] + red[3][i];
    float r0 = r[0] + 1e-8f, r1 = r[1] + 1e-8f, r2 = r[2] + 1e-8f, r3 = r[3] + 1e-8f;
    float off = 2.f * (r[4] / (r0 * r1) + r[5] / (r0 * r2) + r[6] / (r0 * r3)
                     + r[7] / (r1 * r2) + r[8] / (r1 * r3) + r[9] / (r2 * r3));
    offb[b] = off * (1.f / 12.f);   // (Kt*Kt - Kt) = 12
  }
}

__global__ void regfin(const float* __restrict__ offb, float* __restrict__ out) {
  if (threadIdx.x == 0 && blockIdx.x == 0) {
    float s = 0.f;
    for (int i = 0; i < 8; i++) s += offb[i];
    *out = s * (1.f / 8.f);
  }
}

// ---------------- nodes attend to 8 global tokens: one thread per (node, head) ----------------
__global__ void node_attn(const float* __restrict__ Qn, const float* __restrict__ Kg,
                          const float* __restrict__ Vg, float* __restrict__ On,
                          int N, int MAXN)
{
  int gid = blockIdx.x * 256 + threadIdx.x;
  if (gid >= N * H) return;
  int n = gid >> 3, h = gid & 7;
  int b = n / MAXN;
  const float4* q4 = (const float4*)(Qn + (size_t)n * 128 + h * 16);
  float4 q0 = q4[0], q1 = q4[1], q2 = q4[2], q3 = q4[3];
  float l[NGT];
  float mx = -3.0e38f;
#pragma unroll
  for (int tk = 0; tk < NGT; tk++) {
    const float4* k4 = (const float4*)(Kg + (size_t)(b * NGT + tk) * 128 + h * 16);
    float d = dot4(q0, k4[0]) + dot4(q1, k4[1]) + dot4(q2, k4[2]) + dot4(q3, k4[3]);
    l[tk] = d * 0.25f;
    mx = fmaxf(mx, l[tk]);
  }
  float s = 0.f;
#pragma unroll
  for (int tk = 0; tk < NGT; tk++) { l[tk] = expf(l[tk] - mx); s += l[tk]; }
  float inv = 1.f / s;
  float4 a0 = make_float4(0, 0, 0, 0), a1 = a0, a2 = a0, a3 = a0;
#pragma unroll
  for (int tk = 0; tk < NGT; tk++) {
    float p = l[tk] * inv;
    const float4* v4 = (const float4*)(Vg + (size_t)(b * NGT + tk) * 128 + h * 16);
    a0 = scale_madd(a0, 1.f, v4[0], p);
    a1 = scale_madd(a1, 1.f, v4[1], p);
    a2 = scale_madd(a2, 1.f, v4[2], p);
    a3 = scale_madd(a3, 1.f, v4[3], p);
  }
  float4* o4 = (float4*)(On + (size_t)n * 128 + h * 16);
  o4[0] = a0; o4[1] = a1; o4[2] = a2; o4[3] = a3;
}

extern "C" void kernel_launch(void* const* d_in, const int* in_sizes, int n_in,
                              void* d_out, int out_size, void* d_ws, size_t ws_size,
                              hipStream_t stream)
{
  const float* x     = (const float*)d_in[0];
  const int*   ei    = (const int*)d_in[1];
  const float* gh    = (const float*)d_in[2];
  const float* Wq    = (const float*)d_in[6];
  const float* bqv   = (const float*)d_in[7];
  const float* Wk    = (const float*)d_in[8];
  const float* bkv   = (const float*)d_in[9];
  const float* Wv    = (const float*)d_in[10];
  const float* bvv   = (const float*)d_in[11];
  const float* Wsk   = (const float*)d_in[12];
  const float* bsk   = (const float*)d_in[13];
  const float* Wbeta = (const float*)d_in[14];
  const float* ngw   = (const float*)d_in[15];
  const float* ngb   = (const float*)d_in[16];
  const float* ngow  = (const float*)d_in[17];
  const float* ngob  = (const float*)d_in[18];
  const float* gnw   = (const float*)d_in[19];
  const float* gnb   = (const float*)d_in[20];
  const float* gnow  = (const float*)d_in[21];
  const float* gnob  = (const float*)d_in[22];
  const float* W1    = (const float*)d_in[23];
  const float* b1v   = (const float*)d_in[24];
  const float* W2    = (const float*)d_in[25];
  const float* b2v   = (const float*)d_in[26];

  const int N    = in_sizes[0] / D;   // 50000
  const int E    = in_sizes[1] / 2;   // 400000
  const int Bb   = 8;
  const int MAXN = N / Bb;            // 6250

  const int* srcI = ei;
  const int* dstI = ei + E;

  size_t ND = (size_t)N * D;
  float* fw = (float*)d_ws;
  float* w0 = fw;            // q_all -> x1
  float* w1 = fw + ND;       // k_all -> K_all(glob) -> x2
  float* w2 = fw + 2 * ND;   // v_all -> V_all(glob) -> O_nodes -> ff1 (N x 256)
  float* w3 = fw + 3 * ND;   // xr -> out-proj tmp
  float* w4 = fw + 4 * ND;   // attn_out -> Qn -> ff2
  float* misc = fw + 5 * ND;
  float* Qg    = misc;               // 64*128
  float* Og    = Qg + 8192;
  float* gout  = Og + 8192;
  float* Kg    = gout + 8192;
  float* Vg    = Kg + 8192;
  float* m_gl  = Vg + 8192;          // 512
  float* is_gl = m_gl + 512;         // 512
  float* Pbuf  = is_gl + 512;        // 8*4*MAXN
  float* offb  = Pbuf + (size_t)Bb * 4 * MAXN;   // 8 (+pad)
  int* deg       = (int*)(offb + 16);
  int* row_start = deg + N;          // N+1
  int* cursor    = row_start + N + 1;
  int* edge_list = cursor + N;       // E
  // bf16 weight area (16-byte aligned)
  short* wbase = (short*)((((uintptr_t)(edge_list + E)) + 15) & ~(uintptr_t)15);
  short* cWq  = wbase;            // 128x128
  short* cWk  = cWq  + 16384;
  short* cWv  = cWk  + 16384;
  short* cWsk = cWv  + 16384;
  short* cNgK = cWsk + 16384;     // ngw rows 128..256
  short* cNgV = cNgK + 16384;     // ngw rows 256..384
  short* cGnQ = cNgV + 16384;     // gnw rows 0..128
  short* cGnO = cGnQ + 16384;     // gnow
  short* cW1  = cGnO + 16384;     // 256x128
  short* cW2  = cW1  + 32768;     // 128x256

  float* outx   = (float*)d_out;
  float* outgh  = outx + ND;                       // 8192
  float* outreg = outgh + (size_t)Bb * NGT * D;    // 1

  const int GXM = (N + 127) / 128;   // 391
  dim3 blk256(256);

  // one-shot weight conversion
  CvtArgs ca;
  ca.s[0] = Wq;   ca.d[0] = cWq;  ca.n[0] = 16384;
  ca.s[1] = Wk;   ca.d[1] = cWk;  ca.n[1] = 16384;
  ca.s[2] = Wv;   ca.d[2] = cWv;  ca.n[2] = 16384;
  ca.s[3] = Wsk;  ca.d[3] = cWsk; ca.n[3] = 16384;
  ca.s[4] = ngw + 128 * 128; ca.d[4] = cNgK; ca.n[4] = 16384;
  ca.s[5] = ngw + 256 * 128; ca.d[5] = cNgV; ca.n[5] = 16384;
  ca.s[6] = gnw;  ca.d[6] = cGnQ; ca.n[6] = 16384;
  ca.s[7] = gnow; ca.d[7] = cGnO; ca.n[7] = 16384;
  ca.s[8] = W1;   ca.d[8] = cW1;  ca.n[8] = 32768;
  ca.s[9] = W2;   ca.d[9] = cW2;  ca.n[9] = 32768;
  cvt_weights<<<dim3(32, 10), blk256, 0, stream>>>(ca);

  // CSR build (edge list grouped by dst)
  hipMemsetAsync(deg, 0, (size_t)N * sizeof(int), stream);
  count_deg<<<dim3((E + 255) / 256), blk256, 0, stream>>>(dstI, deg, E);
  scan_kernel<<<dim3(1), dim3(1024), 0, stream>>>(deg, row_start, cursor, N, E);
  fill_edges<<<dim3((E + 255) / 256), blk256, 0, stream>>>(dstI, cursor, edge_list, E);

  // tconv projections (MFMA)
  gemm_mfma<<<dim3(GXM, 1), blk256, 0, stream>>>(x, cWq,  bqv, w0, N, 128, 128, 0);
  gemm_mfma<<<dim3(GXM, 1), blk256, 0, stream>>>(x, cWk,  bkv, w1, N, 128, 128, 0);
  gemm_mfma<<<dim3(GXM, 1), blk256, 0, stream>>>(x, cWv,  bvv, w2, N, 128, 128, 0);
  gemm_mfma<<<dim3(GXM, 1), blk256, 0, stream>>>(x, cWsk, bsk, w3, N, 128, 128, 0);

  // edge attention + gate + LN  -> x1 in w0
  tconv_attn<<<dim3((N * H + 255) / 256), blk256, 0, stream>>>(w0, w1, w2, row_start, edge_list, srcI, w4, N);
  gate_ln<<<dim3((N + 3) / 4), blk256, 0, stream>>>(x, w4, w3, Wbeta, w0, N);

  // global MHA (tokens attend over nodes)
  gemm_mfma<<<dim3(GXM, 1), blk256, 0, stream>>>(w0, cNgK, ngb + 128, w1, N, 128, 128, 0); // K_all
  gemm_mfma<<<dim3(GXM, 1), blk256, 0, stream>>>(w0, cNgV, ngb + 256, w2, N, 128, 128, 0); // V_all
  gemm_small<<<dim3(64), dim3(128), 0, stream>>>(gh, ngw, ngb, Qg, 64);
  glob_attn<<<dim3(512), dim3(64), 0, stream>>>(Qg, w1, w2, Og, m_gl, is_gl, MAXN);
  pker<<<dim3(8 * ((MAXN + 255) / 256)), blk256, 0, stream>>>(Qg, w1, m_gl, is_gl, Pbuf, MAXN);
  regk<<<dim3(8), blk256, 0, stream>>>(Pbuf, offb, MAXN);
  regfin<<<dim3(1), dim3(64), 0, stream>>>(offb, outreg);

  gemm_small<<<dim3(64), dim3(128), 0, stream>>>(Og, ngow, ngob, gout, 64);
  ln_add<<<dim3(16), blk256, 0, stream>>>(gh, gout, outgh, 64);   // new global_h -> d_out

  // nodes attend to global tokens
  gemm_small<<<dim3(64), dim3(128), 0, stream>>>(outgh, gnw + 128 * 128, gnb + 128, Kg, 64);
  gemm_small<<<dim3(64), dim3(128), 0, stream>>>(outgh, gnw + 256 * 128, gnb + 256, Vg, 64);
  gemm_mfma<<<dim3(GXM, 1), blk256, 0, stream>>>(w0, cGnQ, gnb, w4, N, 128, 128, 0);   // Qn
  node_attn<<<dim3((N * H + 255) / 256), blk256, 0, stream>>>(w4, Kg, Vg, w2, N, MAXN);
  gemm_mfma<<<dim3(GXM, 1), blk256, 0, stream>>>(w2, cGnO, gnob, w3, N, 128, 128, 0);  // out proj
  ln_add<<<dim3((N + 3) / 4), blk256, 0, stream>>>(w0, w3, w1, N);                     // x2

  // FF + final LN -> d_out x
  gemm_mfma<<<dim3(GXM, 2), blk256, 0, stream>>>(w1, cW1, b1v, w2, N, 128, 256, 1);   // relu(x2@W1.T+b1)
  gemm_mfma<<<dim3(GXM, 1), blk256, 0, stream>>>(w2, cW2, b2v, w4, N, 256, 128, 0);   // @W2.T+b2
  ln_add<<<dim3((N + 3) / 4), blk256, 0, stream>>>(w1, w4, outx, N);
}

// Round 3
// 521.312 us; speedup vs baseline: 2.2617x; 1.1877x over previous
//
#include <hip/hip_runtime.h>
#include <math.h>

#define D 128
#define H 8
#define NGT 8
#define LSTOK 4   // n_global_tokens_global (fixed by problem)

typedef short bf16x8 __attribute__((ext_vector_type(8)));
typedef float f32x4  __attribute__((ext_vector_type(4)));

__device__ __forceinline__ short f2bf(float f) {
  union { float f; unsigned u; } v; v.f = f;
  unsigned r = v.u + 0x7FFFu + ((v.u >> 16) & 1u);   // RNE
  return (short)(r >> 16);
}

__device__ __forceinline__ float dot4(float4 a, float4 b) {
  return a.x*b.x + a.y*b.y + a.z*b.z + a.w*b.w;
}
__device__ __forceinline__ float4 scale_madd(float4 a, float sc, float4 v, float p) {
  return make_float4(fmaf(p, v.x, a.x*sc), fmaf(p, v.y, a.y*sc),
                     fmaf(p, v.z, a.z*sc), fmaf(p, v.w, a.w*sc));
}
__device__ __forceinline__ float4 comb4(float4 a, float e1, float4 c, float e2) {
  return make_float4(a.x*e1 + c.x*e2, a.y*e1 + c.y*e2, a.z*e1 + c.z*e2, a.w*e1 + c.w*e2);
}
__device__ __forceinline__ float4 shfl_xor4(float4 v, int off) {
  return make_float4(__shfl_xor(v.x, off), __shfl_xor(v.y, off),
                     __shfl_xor(v.z, off), __shfl_xor(v.w, off));
}

// ---------------- weight fp32 -> bf16 conversion (one-shot, 10 matrices) ----------------
struct CvtArgs {
  const float* s[10];
  short*       d[10];
  int          n[10];
};

__global__ void cvt_weights(CvtArgs a) {
  int which = blockIdx.y;
  const float* s = a.s[which];
  short* d = a.d[which];
  int n = a.n[which];
  int i = (blockIdx.x * 256 + threadIdx.x) * 4;
  if (i + 3 < n) {
    float4 v = *(const float4*)(s + i);
    d[i]     = f2bf(v.x);
    d[i + 1] = f2bf(v.y);
    d[i + 2] = f2bf(v.z);
    d[i + 3] = f2bf(v.w);
  }
}

__global__ void concat_bias4(const float* __restrict__ b0, const float* __restrict__ b1,
                             const float* __restrict__ b2, const float* __restrict__ b3,
                             float* __restrict__ out) {
  int t = threadIdx.x;
  out[t] = b0[t]; out[128 + t] = b1[t]; out[256 + t] = b2[t]; out[384 + t] = b3[t];
}

// ---------------- MFMA bf16 GEMM: out[r][c] = sum_k A[r][k] * W[c][k] + bias[c] ----------------
// A fp32 row-major [Nrows][K] (row stride == K); Wb bf16 row-major [Ccols][K];
// out fp32 [Nrows][Ccols]. 256 threads, 128x128 tile, wave = 64x64 quadrant.
__global__ void __launch_bounds__(256) gemm_mfma(const float* __restrict__ A,
    const short* __restrict__ Wb, const float* __restrict__ bias,
    float* __restrict__ out, int Nrows, int K, int Ccols, int relu)
{
  __shared__ short As[128 * 136];
  __shared__ short Ws[128 * 136];
  const int t = threadIdx.x;
  const int rowBase = blockIdx.x * 128;
  const int colBase = blockIdx.y * 128;
  const int wid = t >> 6, lane = t & 63;
  const int wr = wid >> 1, wc = wid & 1;

  f32x4 acc[4][4];
  f32x4 z4 = {0.f, 0.f, 0.f, 0.f};
#pragma unroll
  for (int m = 0; m < 4; m++)
#pragma unroll
    for (int n = 0; n < 4; n++) acc[m][n] = z4;

  for (int kout = 0; kout < K; kout += 128) {
#pragma unroll
    for (int it = 0; it < 8; ++it) {
      int chunk = it * 256 + t;
      int r = chunk >> 4, c8 = (chunk & 15) * 8;
      *(bf16x8*)(Ws + r * 136 + c8) =
          *(const bf16x8*)(Wb + (size_t)(colBase + r) * K + kout + c8);
    }
#pragma unroll
    for (int it = 0; it < 8; ++it) {
      int chunk = it * 256 + t;
      int r = chunk >> 4, c8 = (chunk & 15) * 8;
      int gr = rowBase + r;
      bf16x8 v8 = {0, 0, 0, 0, 0, 0, 0, 0};
      if (gr < Nrows) {
        const float* ap = A + (size_t)gr * K + kout + c8;
        float4 f0 = *(const float4*)(ap);
        float4 f1 = *(const float4*)(ap + 4);
        v8[0] = f2bf(f0.x); v8[1] = f2bf(f0.y); v8[2] = f2bf(f0.z); v8[3] = f2bf(f0.w);
        v8[4] = f2bf(f1.x); v8[5] = f2bf(f1.y); v8[6] = f2bf(f1.z); v8[7] = f2bf(f1.w);
      }
      *(bf16x8*)(As + r * 136 + c8) = v8;
    }
    __syncthreads();

    const int lrow = lane & 15;
    const int lk = (lane >> 4) * 8;
#pragma unroll
    for (int kk = 0; kk < 4; ++kk) {
      int kb = kk * 32 + lk;
      bf16x8 af[4], bfr[4];
#pragma unroll
      for (int m = 0; m < 4; ++m)
        af[m] = *(const bf16x8*)(As + (wr * 64 + m * 16 + lrow) * 136 + kb);
#pragma unroll
      for (int n = 0; n < 4; ++n)
        bfr[n] = *(const bf16x8*)(Ws + (wc * 64 + n * 16 + lrow) * 136 + kb);
#pragma unroll
      for (int m = 0; m < 4; ++m)
#pragma unroll
        for (int n = 0; n < 4; ++n)
          acc[m][n] = __builtin_amdgcn_mfma_f32_16x16x32_bf16(af[m], bfr[n], acc[m][n], 0, 0, 0);
    }
    __syncthreads();
  }

  const int ccol = lane & 15;
  const int rquad = (lane >> 4) * 4;
#pragma unroll
  for (int n = 0; n < 4; ++n) {
    int col = colBase + wc * 64 + n * 16 + ccol;
    float bb = bias[col];
#pragma unroll
    for (int m = 0; m < 4; ++m) {
      int row0 = rowBase + wr * 64 + m * 16 + rquad;
#pragma unroll
      for (int r = 0; r < 4; ++r) {
        int gr = row0 + r;
        if (gr < Nrows) {
          float v = acc[m][n][r] + bb;
          if (relu) v = fmaxf(v, 0.f);
          out[(size_t)gr * Ccols + col] = v;
        }
      }
    }
  }
}

// small GEMM (M rows <= 64, K=C=128): one block per row
__global__ void gemm_small(const float* __restrict__ A, const float* __restrict__ W,
                           const float* __restrict__ bias, float* __restrict__ out, int M)
{
  int r = blockIdx.x;
  int c = threadIdx.x;
  __shared__ float as[128];
  as[c] = A[(size_t)r * 128 + c];
  __syncthreads();
  float acc = bias[c];
  const float* wr = W + (size_t)c * 128;
#pragma unroll 4
  for (int k = 0; k < 128; k++) acc += as[k] * wr[k];
  out[(size_t)r * 128 + c] = acc;
}

// ---------------- CSR build ----------------
__global__ void count_deg(const int* __restrict__ dst, int* __restrict__ deg, int E) {
  int e = blockIdx.x * 256 + threadIdx.x;
  if (e < E) atomicAdd(&deg[dst[e]], 1);
}

// segmented scan: pass1 block sums (1024 elems/block of 256 thr)
__global__ void scan_pass1(const int* __restrict__ deg, int* __restrict__ bsum, int N) {
  int t = threadIdx.x, lane = t & 63, wid = t >> 6;
  int idx = blockIdx.x * 1024 + t * 4;
  int4 v = {0, 0, 0, 0};
  if (idx + 3 < N) v = *(const int4*)(deg + idx);
  else {
    if (idx < N) v.x = deg[idx];
    if (idx + 1 < N) v.y = deg[idx + 1];
    if (idx + 2 < N) v.z = deg[idx + 2];
    if (idx + 3 < N) v.w = deg[idx + 3];
  }
  int s = v.x + v.y + v.z + v.w;
#pragma unroll
  for (int off = 32; off >= 1; off >>= 1) s += __shfl_xor(s, off);
  __shared__ int ws[4];
  if (lane == 0) ws[wid] = s;
  __syncthreads();
  if (t == 0) bsum[blockIdx.x] = ws[0] + ws[1] + ws[2] + ws[3];
}

// pass2: exclusive scan of block sums (SB <= 1024), single block
__global__ void scan_pass2(int* __restrict__ bsum, int SB) {
  __shared__ int sh[1024];
  int t = threadIdx.x;
  sh[t] = (t < SB) ? bsum[t] : 0;
  __syncthreads();
  for (int off = 1; off < 1024; off <<= 1) {
    int v = (t >= off) ? sh[t - off] : 0;
    __syncthreads();
    sh[t] += v;
    __syncthreads();
  }
  if (t < SB) bsum[t] = (t == 0) ? 0 : sh[t - 1];
}

// pass3: full exclusive scan -> row_start & cursor
__global__ void scan_pass3(const int* __restrict__ deg, const int* __restrict__ bsum,
                           int* __restrict__ row_start, int* __restrict__ cursor,
                           int N, int E)
{
  int t = threadIdx.x, lane = t & 63, wid = t >> 6;
  int idx = blockIdx.x * 1024 + t * 4;
  int4 v = {0, 0, 0, 0};
  if (idx + 3 < N) v = *(const int4*)(deg + idx);
  else {
    if (idx < N) v.x = deg[idx];
    if (idx + 1 < N) v.y = deg[idx + 1];
    if (idx + 2 < N) v.z = deg[idx + 2];
    if (idx + 3 < N) v.w = deg[idx + 3];
  }
  int ts = v.x + v.y + v.z + v.w;
  int x = ts;
#pragma unroll
  for (int off = 1; off < 64; off <<= 1) {
    int y = __shfl_up(x, off);
    if (lane >= off) x += y;
  }
  __shared__ int ws[4];
  if (lane == 63) ws[wid] = x;
  __syncthreads();
  int woff = 0;
  for (int i = 0; i < wid; i++) woff += ws[i];
  int p = bsum[blockIdx.x] + woff + (x - ts);
  if (idx < N)     { row_start[idx] = p; cursor[idx] = p; }     p += v.x;
  if (idx + 1 < N) { row_start[idx + 1] = p; cursor[idx + 1] = p; } p += v.y;
  if (idx + 2 < N) { row_start[idx + 2] = p; cursor[idx + 2] = p; } p += v.z;
  if (idx + 3 < N) { row_start[idx + 3] = p; cursor[idx + 3] = p; }
  if (blockIdx.x == 0 && t == 0) row_start[N] = E;
}

__global__ void fill_edges(const int* __restrict__ dst, int* __restrict__ cursor,
                           int* __restrict__ edge_list, int E) {
  int e = blockIdx.x * 256 + threadIdx.x;
  if (e < E) {
    int p = atomicAdd(&cursor[dst[e]], 1);
    edge_list[p] = e;
  }
}

// ---------------- tconv edge attention (qkvs fused layout, row stride 512) ----------------
// qkvs[n] = [q(128) | k(128) | v(128) | xr(128)]
__global__ void tconv_attn(const float* __restrict__ qkvs, const int* __restrict__ row_start,
                           const int* __restrict__ edge_list, const int* __restrict__ srcI,
                           float* __restrict__ out, int N)
{
  int gid = blockIdx.x * 256 + threadIdx.x;
  if (gid >= N * H) return;
  int n = gid >> 3, h = gid & 7;
  const float4* q4 = (const float4*)(qkvs + (size_t)n * 512 + h * 16);
  float4 q0 = q4[0], q1 = q4[1], q2 = q4[2], q3 = q4[3];
  float m = -3.0e38f, s = 0.f;
  float4 a0 = make_float4(0, 0, 0, 0), a1 = a0, a2 = a0, a3 = a0;
  int e1 = row_start[n + 1];
  for (int ei = row_start[n]; ei < e1; ei++) {
    int sn = srcI[edge_list[ei]];
    size_t kb = (size_t)sn * 512 + 128 + h * 16;
    const float4* k4 = (const float4*)(qkvs + kb);
    float d = dot4(q0, k4[0]) + dot4(q1, k4[1]) + dot4(q2, k4[2]) + dot4(q3, k4[3]);
    d *= 0.25f;
    float mn = fmaxf(m, d);
    float sc = expf(m - mn);
    float p = expf(d - mn);
    const float4* v4 = (const float4*)(qkvs + kb + 128);
    a0 = scale_madd(a0, sc, v4[0], p);
    a1 = scale_madd(a1, sc, v4[1], p);
    a2 = scale_madd(a2, sc, v4[2], p);
    a3 = scale_madd(a3, sc, v4[3], p);
    s = s * sc + p;
    m = mn;
  }
  float inv = 1.f / (s + 1e-16f);
  float4* o4 = (float4*)(out + (size_t)n * 128 + h * 16);
  o4[0] = make_float4(a0.x * inv, a0.y * inv, a0.z * inv, a0.w * inv);
  o4[1] = make_float4(a1.x * inv, a1.y * inv, a1.z * inv, a1.w * inv);
  o4[2] = make_float4(a2.x * inv, a2.y * inv, a2.z * inv, a2.w * inv);
  o4[3] = make_float4(a3.x * inv, a3.y * inv, a3.z * inv, a3.w * inv);
}

// ---------------- gate + residual + LN; xr has row stride 512 (col 384 of qkvs) ----------------
__global__ void gate_ln(const float* __restrict__ x, const float* __restrict__ att,
                        const float* __restrict__ qkvs, const float* __restrict__ Wb,
                        float* __restrict__ x1, int N)
{
  int wid = threadIdx.x >> 6, lane = threadIdx.x & 63;
  int n = blockIdx.x * 4 + wid;
  if (n >= N) return;
  size_t base = (size_t)n * 128 + lane * 2;
  float2 o = *(const float2*)(att + base);
  float2 r = *(const float2*)(qkvs + (size_t)n * 512 + 384 + lane * 2);
  float2 xv = *(const float2*)(x + base);
  float2 w0 = *(const float2*)(Wb + lane * 2);
  float2 w1 = *(const float2*)(Wb + 128 + lane * 2);
  float2 w2 = *(const float2*)(Wb + 256 + lane * 2);
  float ts = o.x * w0.x + o.y * w0.y + r.x * w1.x + r.y * w1.y
           + (o.x - r.x) * w2.x + (o.y - r.y) * w2.y;
#pragma unroll
  for (int mm = 32; mm >= 1; mm >>= 1) ts += __shfl_xor(ts, mm);
  float beta = 1.f / (1.f + expf(-ts));
  float2 y;
  y.x = xv.x + beta * r.x + (1.f - beta) * o.x;
  y.y = xv.y + beta * r.y + (1.f - beta) * o.y;
  float sm = y.x + y.y;
#pragma unroll
  for (int mm = 32; mm >= 1; mm >>= 1) sm += __shfl_xor(sm, mm);
  float mean = sm * (1.f / 128.f);
  float dx = y.x - mean, dy = y.y - mean;
  float vs = dx * dx + dy * dy;
#pragma unroll
  for (int mm = 32; mm >= 1; mm >>= 1) vs += __shfl_xor(vs, mm);
  float rstd = rsqrtf(vs * (1.f / 128.f) + 1e-5f);
  *(float2*)(x1 + base) = make_float2(dx * rstd, dy * rstd);
}

// ---------------- out = LN(a + b); one wave per row ----------------
__global__ void ln_add(const float* __restrict__ a, const float* __restrict__ b,
                       float* __restrict__ out, int R)
{
  int wid = threadIdx.x >> 6, lane = threadIdx.x & 63;
  int r = blockIdx.x * 4 + wid;
  if (r >= R) return;
  size_t base = (size_t)r * 128 + lane * 2;
  float2 av = *(const float2*)(a + base);
  float2 bv = *(const float2*)(b + base);
  float2 y = make_float2(av.x + bv.x, av.y + bv.y);
  float sm = y.x + y.y;
#pragma unroll
  for (int mm = 32; mm >= 1; mm >>= 1) sm += __shfl_xor(sm, mm);
  float mean = sm * (1.f / 128.f);
  float dx = y.x - mean, dy = y.y - mean;
  float vs = dx * dx + dy * dy;
#pragma unroll
  for (int mm = 32; mm >= 1; mm >>= 1) vs += __shfl_xor(vs, mm);
  float rstd = rsqrtf(vs * (1.f / 128.f) + 1e-5f);
  *(float2*)(out + base) = make_float2(dx * rstd, dy * rstd);
}

// ---------------- global tokens attend over nodes (kv fused layout stride 256) ----------------
__global__ void glob_attn(const float* __restrict__ Qg, const float* __restrict__ kv,
                          float* __restrict__ Og,
                          float* __restrict__ m_gl, float* __restrict__ is_gl, int MAXN)
{
  int blk = blockIdx.x;                 // b*64 + g*8 + h
  int h = blk & 7, g = (blk >> 3) & 7, b = blk >> 6;
  int lane = threadIdx.x;
  const float4* q4 = (const float4*)(Qg + (size_t)(b * NGT + g) * 128 + h * 16);
  float4 q0 = q4[0], q1 = q4[1], q2 = q4[2], q3 = q4[3];
  float m = -3.0e38f, s = 0.f;
  float4 a0 = make_float4(0, 0, 0, 0), a1 = a0, a2 = a0, a3 = a0;
  for (int n = lane; n < MAXN; n += 64) {
    size_t base = ((size_t)(b * MAXN + n)) * 256 + h * 16;
    const float4* k4 = (const float4*)(kv + base);
    float d = dot4(q0, k4[0]) + dot4(q1, k4[1]) + dot4(q2, k4[2]) + dot4(q3, k4[3]);
    d *= 0.25f;
    float mn = fmaxf(m, d);
    float sc = expf(m - mn);
    float p = expf(d - mn);
    const float4* v4 = (const float4*)(kv + base + 128);
    a0 = scale_madd(a0, sc, v4[0], p);
    a1 = scale_madd(a1, sc, v4[1], p);
    a2 = scale_madd(a2, sc, v4[2], p);
    a3 = scale_madd(a3, sc, v4[3], p);
    s = s * sc + p;
    m = mn;
  }
#pragma unroll
  for (int off = 32; off >= 1; off >>= 1) {
    float m2 = __shfl_xor(m, off);
    float s2 = __shfl_xor(s, off);
    float4 c0 = shfl_xor4(a0, off), c1 = shfl_xor4(a1, off);
    float4 c2 = shfl_xor4(a2, off), c3 = shfl_xor4(a3, off);
    float mn = fmaxf(m, m2);
    float e1 = expf(m - mn), e2 = expf(m2 - mn);
    s = s * e1 + s2 * e2;
    a0 = comb4(a0, e1, c0, e2);
    a1 = comb4(a1, e1, c1, e2);
    a2 = comb4(a2, e1, c2, e2);
    a3 = comb4(a3, e1, c3, e2);
    m = mn;
  }
  if (lane == 0) {
    float inv = 1.f / s;
    float4* o4 = (float4*)(Og + (size_t)(b * NGT + g) * 128 + h * 16);
    o4[0] = make_float4(a0.x * inv, a0.y * inv, a0.z * inv, a0.w * inv);
    o4[1] = make_float4(a1.x * inv, a1.y * inv, a1.z * inv, a1.w * inv);
    o4[2] = make_float4(a2.x * inv, a2.y * inv, a2.z * inv, a2.w * inv);
    o4[3] = make_float4(a3.x * inv, a3.y * inv, a3.z * inv, a3.w * inv);
    m_gl[blk] = m;
    is_gl[blk] = inv;
  }
}

// ---------------- P rows (kv stride 256) ----------------
__global__ void pker(const float* __restrict__ Qg, const float* __restrict__ kv,
                     const float* __restrict__ m_gl, const float* __restrict__ is_gl,
                     float* __restrict__ P, int MAXN)
{
  int nchunk = (MAXN + 255) >> 8;
  int b = blockIdx.x / nchunk;
  int ch = blockIdx.x % nchunk;
  __shared__ float qs[4 * 128];
  __shared__ float ms[32], iss[32];
  for (int i = threadIdx.x; i < 512; i += 256)
    qs[i] = Qg[(size_t)(b * NGT + LSTOK) * 128 + i];
  if (threadIdx.x < 32) {
    int g = threadIdx.x >> 3, h = threadIdx.x & 7;
    ms[threadIdx.x]  = m_gl[(b * NGT + LSTOK + g) * H + h];
    iss[threadIdx.x] = is_gl[(b * NGT + LSTOK + g) * H + h];
  }
  __syncthreads();
  int n = ch * 256 + threadIdx.x;
  if (n >= MAXN) return;
  float acc[4] = {0.f, 0.f, 0.f, 0.f};
  size_t kbase = ((size_t)(b * MAXN + n)) * 256;
  for (int h = 0; h < H; h++) {
    const float4* k4 = (const float4*)(kv + kbase + h * 16);
    float4 k0 = k4[0], k1 = k4[1], k2 = k4[2], k3 = k4[3];
#pragma unroll
    for (int g = 0; g < 4; g++) {
      const float4* qp = (const float4*)(qs + g * 128 + h * 16);
      float d = dot4(k0, qp[0]) + dot4(k1, qp[1]) + dot4(k2, qp[2]) + dot4(k3, qp[3]);
      d *= 0.25f;
      acc[g] += expf(d - ms[g * 8 + h]) * iss[g * 8 + h];
    }
  }
#pragma unroll
  for (int g = 0; g < 4; g++)
    P[(size_t)(b * 4 + g) * MAXN + n] = acc[g] * 0.125f;
}

// ---------------- reg: off-diagonal Gram of row-normalized P ----------------
__global__ void regk(const float* __restrict__ P, float* __restrict__ offb, int MAXN)
{
  int b = blockIdx.x;
  int t = threadIdx.x;
  float v[10];
#pragma unroll
  for (int i = 0; i < 10; i++) v[i] = 0.f;
  for (int n = t; n < MAXN; n += 256) {
    float p0 = P[(size_t)(b * 4 + 0) * MAXN + n];
    float p1 = P[(size_t)(b * 4 + 1) * MAXN + n];
    float p2 = P[(size_t)(b * 4 + 2) * MAXN + n];
    float p3 = P[(size_t)(b * 4 + 3) * MAXN + n];
    v[0] += p0; v[1] += p1; v[2] += p2; v[3] += p3;
    v[4] += p0 * p1; v[5] += p0 * p2; v[6] += p0 * p3;
    v[7] += p1 * p2; v[8] += p1 * p3; v[9] += p2 * p3;
  }
#pragma unroll
  for (int i = 0; i < 10; i++) {
    float x = v[i];
#pragma unroll
    for (int mm = 32; mm >= 1; mm >>= 1) x += __shfl_xor(x, mm);
    v[i] = x;
  }
  __shared__ float red[4][10];
  int wid = t >> 6, lane = t & 63;
  if (lane == 0)
    for (int i = 0; i < 10; i++) red[wid][i] = v[i];
  __syncthreads();
  if (t == 0) {
    float r[10];
    for (int i = 0; i < 10; i++) r[i] = red[0][i] + red[1][i] + red[2][i] + red[3][i];
    float r0 = r[0] + 1e-8f, r1 = r[1] + 1e-8f, r2 = r[2] + 1e-8f, r3 = r[3] + 1e-8f;
    float off = 2.f * (r[4] / (r0 * r1) + r[5] / (r0 * r2) + r[6] / (r0 * r3)
                     + r[7] / (r1 * r2) + r[8] / (r1 * r3) + r[9] / (r2 * r3));
    offb[b] = off * (1.f / 12.f);   // (Kt*Kt - Kt) = 12
  }
}

__global__ void regfin(const float* __restrict__ offb, float* __restrict__ out) {
  if (threadIdx.x == 0 && blockIdx.x == 0) {
    float s = 0.f;
    for (int i = 0; i < 8; i++) s += offb[i];
    *out = s * (1.f / 8.f);
  }
}

// ---------------- nodes attend to 8 global tokens ----------------
__global__ void node_attn(const float* __restrict__ Qn, const float* __restrict__ Kg,
                          const float* __restrict__ Vg, float* __restrict__ On,
                          int N, int MAXN)
{
  int gid = blockIdx.x * 256 + threadIdx.x;
  if (gid >= N * H) return;
  int n = gid >> 3, h = gid & 7;
  int b = n / MAXN;
  const float4* q4 = (const float4*)(Qn + (size_t)n * 128 + h * 16);
  float4 q0 = q4[0], q1 = q4[1], q2 = q4[2], q3 = q4[3];
  float l[NGT];
  float mx = -3.0e38f;
#pragma unroll
  for (int tk = 0; tk < NGT; tk++) {
    const float4* k4 = (const float4*)(Kg + (size_t)(b * NGT + tk) * 128 + h * 16);
    float d = dot4(q0, k4[0]) + dot4(q1, k4[1]) + dot4(q2, k4[2]) + dot4(q3, k4[3]);
    l[tk] = d * 0.25f;
    mx = fmaxf(mx, l[tk]);
  }
  float s = 0.f;
#pragma unroll
  for (int tk = 0; tk < NGT; tk++) { l[tk] = expf(l[tk] - mx); s += l[tk]; }
  float inv = 1.f / s;
  float4 a0 = make_float4(0, 0, 0, 0), a1 = a0, a2 = a0, a3 = a0;
#pragma unroll
  for (int tk = 0; tk < NGT; tk++) {
    float p = l[tk] * inv;
    const float4* v4 = (const float4*)(Vg + (size_t)(b * NGT + tk) * 128 + h * 16);
    a0 = scale_madd(a0, 1.f, v4[0], p);
    a1 = scale_madd(a1, 1.f, v4[1], p);
    a2 = scale_madd(a2, 1.f, v4[2], p);
    a3 = scale_madd(a3, 1.f, v4[3], p);
  }
  float4* o4 = (float4*)(On + (size_t)n * 128 + h * 16);
  o4[0] = a0; o4[1] = a1; o4[2] = a2; o4[3] = a3;
}

extern "C" void kernel_launch(void* const* d_in, const int* in_sizes, int n_in,
                              void* d_out, int out_size, void* d_ws, size_t ws_size,
                              hipStream_t stream)
{
  const float* x     = (const float*)d_in[0];
  const int*   ei    = (const int*)d_in[1];
  const float* gh    = (const float*)d_in[2];
  const float* Wq    = (const float*)d_in[6];
  const float* bqv   = (const float*)d_in[7];
  const float* Wk    = (const float*)d_in[8];
  const float* bkv   = (const float*)d_in[9];
  const float* Wv    = (const float*)d_in[10];
  const float* bvv   = (const float*)d_in[11];
  const float* Wsk   = (const float*)d_in[12];
  const float* bsk   = (const float*)d_in[13];
  const float* Wbeta = (const float*)d_in[14];
  const float* ngw   = (const float*)d_in[15];
  const float* ngb   = (const float*)d_in[16];
  const float* ngow  = (const float*)d_in[17];
  const float* ngob  = (const float*)d_in[18];
  const float* gnw   = (const float*)d_in[19];
  const float* gnb   = (const float*)d_in[20];
  const float* gnow  = (const float*)d_in[21];
  const float* gnob  = (const float*)d_in[22];
  const float* W1    = (const float*)d_in[23];
  const float* b1v   = (const float*)d_in[24];
  const float* W2    = (const float*)d_in[25];
  const float* b2v   = (const float*)d_in[26];

  const int N    = in_sizes[0] / D;   // 50000
  const int E    = in_sizes[1] / 2;   // 400000
  const int Bb   = 8;
  const int MAXN = N / Bb;            // 6250

  const int* srcI = ei;
  const int* dstI = ei + E;

  size_t ND = (size_t)N * D;
  float* fw = (float*)d_ws;
  // fw[0..4ND): A region = qkvs (N x 512); later: kv (N x 256) at +0,
  //   Qn at +2ND, node-attn out at +3ND, ff1 (N x 256) at +0, ff2 at +2ND.
  float* qkvs = fw;
  float* wx1  = fw + 4 * ND;          // x1 (persists; x2 in-place later)
  float* misc = fw + 5 * ND;
  float* Qg    = misc;                // 64*128
  float* Og    = Qg + 8192;
  float* gout  = Og + 8192;
  float* Kg    = gout + 8192;
  float* Vg    = Kg + 8192;
  float* m_gl  = Vg + 8192;           // 512
  float* is_gl = m_gl + 512;          // 512
  float* Pbuf  = is_gl + 512;         // 8*4*MAXN
  float* offb  = Pbuf + (size_t)Bb * 4 * MAXN;   // 8 (+pad)
  float* bias512 = offb + 16;         // 512
  int* deg       = (int*)(bias512 + 512);
  int* row_start = deg + N;           // N+1
  int* cursor    = row_start + N + 1;
  int* bsum      = cursor + N;        // <=1024
  int* edge_list = bsum + 1024;       // E
  short* wbase = (short*)((((uintptr_t)(edge_list + E)) + 15) & ~(uintptr_t)15);
  short* cWq  = wbase;            // 4 x 128x128 stacked -> 512x128
  short* cWk  = cWq  + 16384;
  short* cWv  = cWk  + 16384;
  short* cWsk = cWv  + 16384;
  short* cNgK = cWsk + 16384;     // 2 x 128x128 stacked -> 256x128
  short* cNgV = cNgK + 16384;
  short* cGnQ = cNgV + 16384;
  short* cGnO = cGnQ + 16384;
  short* cW1  = cGnO + 16384;     // 256x128
  short* cW2  = cW1  + 32768;     // 128x256

  float* outx   = (float*)d_out;
  float* outgh  = outx + ND;                       // 8192
  float* outreg = outgh + (size_t)Bb * NGT * D;    // 1
  float* wa     = outx;   // scratch: tconv att-out, later out-proj result

  const int GXM = (N + 127) / 128;    // 391
  const int SB  = (N + 1023) / 1024;  // 49
  dim3 blk256(256);

  // one-shot weight conversion + bias concat
  CvtArgs ca;
  ca.s[0] = Wq;   ca.d[0] = cWq;  ca.n[0] = 16384;
  ca.s[1] = Wk;   ca.d[1] = cWk;  ca.n[1] = 16384;
  ca.s[2] = Wv;   ca.d[2] = cWv;  ca.n[2] = 16384;
  ca.s[3] = Wsk;  ca.d[3] = cWsk; ca.n[3] = 16384;
  ca.s[4] = ngw + 128 * 128; ca.d[4] = cNgK; ca.n[4] = 16384;
  ca.s[5] = ngw + 256 * 128; ca.d[5] = cNgV; ca.n[5] = 16384;
  ca.s[6] = gnw;  ca.d[6] = cGnQ; ca.n[6] = 16384;
  ca.s[7] = gnow; ca.d[7] = cGnO; ca.n[7] = 16384;
  ca.s[8] = W1;   ca.d[8] = cW1;  ca.n[8] = 32768;
  ca.s[9] = W2;   ca.d[9] = cW2;  ca.n[9] = 32768;
  cvt_weights<<<dim3(32, 10), blk256, 0, stream>>>(ca);
  concat_bias4<<<dim3(1), dim3(128), 0, stream>>>(bqv, bkv, bvv, bsk, bias512);

  // CSR build
  hipMemsetAsync(deg, 0, (size_t)N * sizeof(int), stream);
  count_deg<<<dim3((E + 255) / 256), blk256, 0, stream>>>(dstI, deg, E);
  scan_pass1<<<dim3(SB), blk256, 0, stream>>>(deg, bsum, N);
  scan_pass2<<<dim3(1), dim3(1024), 0, stream>>>(bsum, SB);
  scan_pass3<<<dim3(SB), blk256, 0, stream>>>(deg, bsum, row_start, cursor, N, E);
  fill_edges<<<dim3((E + 255) / 256), blk256, 0, stream>>>(dstI, cursor, edge_list, E);

  // fused tconv projections: qkvs = x @ [Wq;Wk;Wv;Wskip]^T + bias512   (N x 512)
  gemm_mfma<<<dim3(GXM, 4), blk256, 0, stream>>>(x, cWq, bias512, qkvs, N, 128, 512, 0);

  // edge attention + gate + LN  -> x1
  tconv_attn<<<dim3((N * H + 255) / 256), blk256, 0, stream>>>(qkvs, row_start, edge_list, srcI, wa, N);
  gate_ln<<<dim3((N + 3) / 4), blk256, 0, stream>>>(x, wa, qkvs, Wbeta, wx1, N);

  // global MHA: fused K|V projection (N x 256)
  gemm_mfma<<<dim3(GXM, 2), blk256, 0, stream>>>(wx1, cNgK, ngb + 128, fw, N, 128, 256, 0);
  gemm_small<<<dim3(64), dim3(128), 0, stream>>>(gh, ngw, ngb, Qg, 64);
  glob_attn<<<dim3(512), dim3(64), 0, stream>>>(Qg, fw, Og, m_gl, is_gl, MAXN);
  pker<<<dim3(8 * ((MAXN + 255) / 256)), blk256, 0, stream>>>(Qg, fw, m_gl, is_gl, Pbuf, MAXN);
  regk<<<dim3(8), blk256, 0, stream>>>(Pbuf, offb, MAXN);
  regfin<<<dim3(1), dim3(64), 0, stream>>>(offb, outreg);

  gemm_small<<<dim3(64), dim3(128), 0, stream>>>(Og, ngow, ngob, gout, 64);
  ln_add<<<dim3(16), blk256, 0, stream>>>(gh, gout, outgh, 64);   // new global_h

  // nodes attend to global tokens
  gemm_small<<<dim3(64), dim3(128), 0, stream>>>(outgh, gnw + 128 * 128, gnb + 128, Kg, 64);
  gemm_small<<<dim3(64), dim3(128), 0, stream>>>(outgh, gnw + 256 * 128, gnb + 256, Vg, 64);
  gemm_mfma<<<dim3(GXM, 1), blk256, 0, stream>>>(wx1, cGnQ, gnb, fw + 2 * ND, N, 128, 128, 0);  // Qn
  node_attn<<<dim3((N * H + 255) / 256), blk256, 0, stream>>>(fw + 2 * ND, Kg, Vg, fw + 3 * ND, N, MAXN);
  gemm_mfma<<<dim3(GXM, 1), blk256, 0, stream>>>(fw + 3 * ND, cGnO, gnob, wa, N, 128, 128, 0);  // out proj
  ln_add<<<dim3((N + 3) / 4), blk256, 0, stream>>>(wx1, wa, wx1, N);   // x2 (in place)

  // FF + final LN -> d_out x
  gemm_mfma<<<dim3(GXM, 2), blk256, 0, stream>>>(wx1, cW1, b1v, fw, N, 128, 256, 1);          // ff1
  gemm_mfma<<<dim3(GXM, 1), blk256, 0, stream>>>(fw, cW2, b2v, fw + 2 * ND, N, 256, 128, 0);  // ff2
  ln_add<<<dim3((N + 3) / 4), blk256, 0, stream>>>(wx1, fw + 2 * ND, outx, N);
}

// Round 4
// 461.197 us; speedup vs baseline: 2.5565x; 1.1303x over previous
//
#include <hip/hip_runtime.h>
#include <math.h>

#define D 128
#define H 8
#define NGT 8
#define LSTOK 4   // n_global_tokens_global (fixed by problem)

typedef short bf16x8 __attribute__((ext_vector_type(8)));
typedef float f32x4  __attribute__((ext_vector_type(4)));

__device__ __forceinline__ short f2bf(float f) {
  union { float f; unsigned u; } v; v.f = f;
  unsigned r = v.u + 0x7FFFu + ((v.u >> 16) & 1u);   // RNE
  return (short)(r >> 16);
}
__device__ __forceinline__ float bf2f(short s) {
  union { unsigned u; float f; } v;
  v.u = ((unsigned)(unsigned short)s) << 16;
  return v.f;
}
__device__ __forceinline__ float4 bf4(bf16x8 v, int lo) {
  return make_float4(bf2f(v[lo]), bf2f(v[lo + 1]), bf2f(v[lo + 2]), bf2f(v[lo + 3]));
}

__device__ __forceinline__ float dot4(float4 a, float4 b) {
  return a.x*b.x + a.y*b.y + a.z*b.z + a.w*b.w;
}
__device__ __forceinline__ float4 scale_madd(float4 a, float sc, float4 v, float p) {
  return make_float4(fmaf(p, v.x, a.x*sc), fmaf(p, v.y, a.y*sc),
                     fmaf(p, v.z, a.z*sc), fmaf(p, v.w, a.w*sc));
}
__device__ __forceinline__ float4 comb4(float4 a, float e1, float4 c, float e2) {
  return make_float4(a.x*e1 + c.x*e2, a.y*e1 + c.y*e2, a.z*e1 + c.z*e2, a.w*e1 + c.w*e2);
}
__device__ __forceinline__ float4 shfl_xor4(float4 v, int off) {
  return make_float4(__shfl_xor(v.x, off), __shfl_xor(v.y, off),
                     __shfl_xor(v.z, off), __shfl_xor(v.w, off));
}

// ---------------- weight fp32 -> bf16 conversion (one-shot, 10 matrices) ----------------
struct CvtArgs {
  const float* s[10];
  short*       d[10];
  int          n[10];
};

__global__ void cvt_weights(CvtArgs a) {
  int which = blockIdx.y;
  const float* s = a.s[which];
  short* d = a.d[which];
  int n = a.n[which];
  int i = (blockIdx.x * 256 + threadIdx.x) * 4;
  if (i + 3 < n) {
    float4 v = *(const float4*)(s + i);
    d[i]     = f2bf(v.x);
    d[i + 1] = f2bf(v.y);
    d[i + 2] = f2bf(v.z);
    d[i + 3] = f2bf(v.w);
  }
}

__global__ void concat_bias4(const float* __restrict__ b0, const float* __restrict__ b1,
                             const float* __restrict__ b2, const float* __restrict__ b3,
                             float* __restrict__ out) {
  int t = threadIdx.x;
  out[t] = b0[t]; out[128 + t] = b1[t]; out[256 + t] = b2[t]; out[384 + t] = b3[t];
}

// ---------------- MFMA bf16 GEMM: out[r][c] = sum_k A[r][k] * W[c][k] + bias[c] ----------------
// Optionally also emits bf16 copy of columns [c16lo, c16lo+256) into out16 (row stride 256).
__global__ void __launch_bounds__(256) gemm_mfma(const float* __restrict__ A,
    const short* __restrict__ Wb, const float* __restrict__ bias,
    float* __restrict__ out, int Nrows, int K, int Ccols, int relu,
    short* __restrict__ out16, int c16lo)
{
  __shared__ short As[128 * 136];
  __shared__ short Ws[128 * 136];
  const int t = threadIdx.x;
  const int rowBase = blockIdx.x * 128;
  const int colBase = blockIdx.y * 128;
  const int wid = t >> 6, lane = t & 63;
  const int wr = wid >> 1, wc = wid & 1;

  f32x4 acc[4][4];
  f32x4 z4 = {0.f, 0.f, 0.f, 0.f};
#pragma unroll
  for (int m = 0; m < 4; m++)
#pragma unroll
    for (int n = 0; n < 4; n++) acc[m][n] = z4;

  for (int kout = 0; kout < K; kout += 128) {
#pragma unroll
    for (int it = 0; it < 8; ++it) {
      int chunk = it * 256 + t;
      int r = chunk >> 4, c8 = (chunk & 15) * 8;
      *(bf16x8*)(Ws + r * 136 + c8) =
          *(const bf16x8*)(Wb + (size_t)(colBase + r) * K + kout + c8);
    }
#pragma unroll
    for (int it = 0; it < 8; ++it) {
      int chunk = it * 256 + t;
      int r = chunk >> 4, c8 = (chunk & 15) * 8;
      int gr = rowBase + r;
      bf16x8 v8 = {0, 0, 0, 0, 0, 0, 0, 0};
      if (gr < Nrows) {
        const float* ap = A + (size_t)gr * K + kout + c8;
        float4 f0 = *(const float4*)(ap);
        float4 f1 = *(const float4*)(ap + 4);
        v8[0] = f2bf(f0.x); v8[1] = f2bf(f0.y); v8[2] = f2bf(f0.z); v8[3] = f2bf(f0.w);
        v8[4] = f2bf(f1.x); v8[5] = f2bf(f1.y); v8[6] = f2bf(f1.z); v8[7] = f2bf(f1.w);
      }
      *(bf16x8*)(As + r * 136 + c8) = v8;
    }
    __syncthreads();

    const int lrow = lane & 15;
    const int lk = (lane >> 4) * 8;
#pragma unroll
    for (int kk = 0; kk < 4; ++kk) {
      int kb = kk * 32 + lk;
      bf16x8 af[4], bfr[4];
#pragma unroll
      for (int m = 0; m < 4; ++m)
        af[m] = *(const bf16x8*)(As + (wr * 64 + m * 16 + lrow) * 136 + kb);
#pragma unroll
      for (int n = 0; n < 4; ++n)
        bfr[n] = *(const bf16x8*)(Ws + (wc * 64 + n * 16 + lrow) * 136 + kb);
#pragma unroll
      for (int m = 0; m < 4; ++m)
#pragma unroll
        for (int n = 0; n < 4; ++n)
          acc[m][n] = __builtin_amdgcn_mfma_f32_16x16x32_bf16(af[m], bfr[n], acc[m][n], 0, 0, 0);
    }
    __syncthreads();
  }

  const int ccol = lane & 15;
  const int rquad = (lane >> 4) * 4;
#pragma unroll
  for (int n = 0; n < 4; ++n) {
    int col = colBase + wc * 64 + n * 16 + ccol;
    float bb = bias[col];
    int cc16 = col - c16lo;           // bf16 side-channel column
#pragma unroll
    for (int m = 0; m < 4; ++m) {
      int row0 = rowBase + wr * 64 + m * 16 + rquad;
#pragma unroll
      for (int r = 0; r < 4; ++r) {
        int gr = row0 + r;
        if (gr < Nrows) {
          float v = acc[m][n][r] + bb;
          if (relu) v = fmaxf(v, 0.f);
          out[(size_t)gr * Ccols + col] = v;
          if (out16 && cc16 >= 0 && cc16 < 256)
            out16[(size_t)gr * 256 + cc16] = f2bf(v);
        }
      }
    }
  }
}

// small GEMM (M rows <= 64, K=C=128): one block per row
__global__ void gemm_small(const float* __restrict__ A, const float* __restrict__ W,
                           const float* __restrict__ bias, float* __restrict__ out, int M)
{
  int r = blockIdx.x;
  int c = threadIdx.x;
  __shared__ float as[128];
  as[c] = A[(size_t)r * 128 + c];
  __syncthreads();
  float acc = bias[c];
  const float* wr = W + (size_t)c * 128;
#pragma unroll 4
  for (int k = 0; k < 128; k++) acc += as[k] * wr[k];
  out[(size_t)r * 128 + c] = acc;
}

// ---------------- CSR build ----------------
__global__ void count_deg(const int* __restrict__ dst, int* __restrict__ deg, int E) {
  int e = blockIdx.x * 256 + threadIdx.x;
  if (e < E) atomicAdd(&deg[dst[e]], 1);
}

__global__ void scan_pass1(const int* __restrict__ deg, int* __restrict__ bsum, int N) {
  int t = threadIdx.x, lane = t & 63, wid = t >> 6;
  int idx = blockIdx.x * 1024 + t * 4;
  int4 v = {0, 0, 0, 0};
  if (idx + 3 < N) v = *(const int4*)(deg + idx);
  else {
    if (idx < N) v.x = deg[idx];
    if (idx + 1 < N) v.y = deg[idx + 1];
    if (idx + 2 < N) v.z = deg[idx + 2];
    if (idx + 3 < N) v.w = deg[idx + 3];
  }
  int s = v.x + v.y + v.z + v.w;
#pragma unroll
  for (int off = 32; off >= 1; off >>= 1) s += __shfl_xor(s, off);
  __shared__ int ws[4];
  if (lane == 0) ws[wid] = s;
  __syncthreads();
  if (t == 0) bsum[blockIdx.x] = ws[0] + ws[1] + ws[2] + ws[3];
}

__global__ void scan_pass2(int* __restrict__ bsum, int SB) {
  __shared__ int sh[1024];
  int t = threadIdx.x;
  sh[t] = (t < SB) ? bsum[t] : 0;
  __syncthreads();
  for (int off = 1; off < 1024; off <<= 1) {
    int v = (t >= off) ? sh[t - off] : 0;
    __syncthreads();
    sh[t] += v;
    __syncthreads();
  }
  if (t < SB) bsum[t] = (t == 0) ? 0 : sh[t - 1];
}

__global__ void scan_pass3(const int* __restrict__ deg, const int* __restrict__ bsum,
                           int* __restrict__ row_start, int* __restrict__ cursor,
                           int N, int E)
{
  int t = threadIdx.x, lane = t & 63, wid = t >> 6;
  int idx = blockIdx.x * 1024 + t * 4;
  int4 v = {0, 0, 0, 0};
  if (idx + 3 < N) v = *(const int4*)(deg + idx);
  else {
    if (idx < N) v.x = deg[idx];
    if (idx + 1 < N) v.y = deg[idx + 1];
    if (idx + 2 < N) v.z = deg[idx + 2];
    if (idx + 3 < N) v.w = deg[idx + 3];
  }
  int ts = v.x + v.y + v.z + v.w;
  int x = ts;
#pragma unroll
  for (int off = 1; off < 64; off <<= 1) {
    int y = __shfl_up(x, off);
    if (lane >= off) x += y;
  }
  __shared__ int ws[4];
  if (lane == 63) ws[wid] = x;
  __syncthreads();
  int woff = 0;
  for (int i = 0; i < wid; i++) woff += ws[i];
  int p = bsum[blockIdx.x] + woff + (x - ts);
  if (idx < N)     { row_start[idx] = p; cursor[idx] = p; }     p += v.x;
  if (idx + 1 < N) { row_start[idx + 1] = p; cursor[idx + 1] = p; } p += v.y;
  if (idx + 2 < N) { row_start[idx + 2] = p; cursor[idx + 2] = p; } p += v.z;
  if (idx + 3 < N) { row_start[idx + 3] = p; cursor[idx + 3] = p; }
  if (blockIdx.x == 0 && t == 0) row_start[N] = E;
}

__global__ void fill_edges(const int* __restrict__ dst, int* __restrict__ cursor,
                           int* __restrict__ edge_list, int E) {
  int e = blockIdx.x * 256 + threadIdx.x;
  if (e < E) {
    int p = atomicAdd(&cursor[dst[e]], 1);
    edge_list[p] = e;
  }
}

// ---------------- tconv edge attention: q fp32 (qkvs stride 512), k/v bf16 (kvb stride 256) ----
__global__ void tconv_attn(const float* __restrict__ qkvs, const short* __restrict__ kvb,
                           const int* __restrict__ row_start,
                           const int* __restrict__ edge_list, const int* __restrict__ srcI,
                           float* __restrict__ out, int N)
{
  int gid = blockIdx.x * 256 + threadIdx.x;
  if (gid >= N * H) return;
  int n = gid >> 3, h = gid & 7;
  const float4* q4 = (const float4*)(qkvs + (size_t)n * 512 + h * 16);
  float4 q0 = q4[0], q1 = q4[1], q2 = q4[2], q3 = q4[3];
  float m = -3.0e38f, s = 0.f;
  float4 a0 = make_float4(0, 0, 0, 0), a1 = a0, a2 = a0, a3 = a0;
  int e1 = row_start[n + 1];
  for (int ei = row_start[n]; ei < e1; ei++) {
    int sn = srcI[edge_list[ei]];
    const short* kp = kvb + (size_t)sn * 256 + h * 16;
    bf16x8 k0 = *(const bf16x8*)(kp);
    bf16x8 k1 = *(const bf16x8*)(kp + 8);
    float d = dot4(q0, bf4(k0, 0)) + dot4(q1, bf4(k0, 4))
            + dot4(q2, bf4(k1, 0)) + dot4(q3, bf4(k1, 4));
    d *= 0.25f;
    float mn = fmaxf(m, d);
    float sc = expf(m - mn);
    float p = expf(d - mn);
    bf16x8 v0 = *(const bf16x8*)(kp + 128);
    bf16x8 v1 = *(const bf16x8*)(kp + 136);
    a0 = scale_madd(a0, sc, bf4(v0, 0), p);
    a1 = scale_madd(a1, sc, bf4(v0, 4), p);
    a2 = scale_madd(a2, sc, bf4(v1, 0), p);
    a3 = scale_madd(a3, sc, bf4(v1, 4), p);
    s = s * sc + p;
    m = mn;
  }
  float inv = 1.f / (s + 1e-16f);
  float4* o4 = (float4*)(out + (size_t)n * 128 + h * 16);
  o4[0] = make_float4(a0.x * inv, a0.y * inv, a0.z * inv, a0.w * inv);
  o4[1] = make_float4(a1.x * inv, a1.y * inv, a1.z * inv, a1.w * inv);
  o4[2] = make_float4(a2.x * inv, a2.y * inv, a2.z * inv, a2.w * inv);
  o4[3] = make_float4(a3.x * inv, a3.y * inv, a3.z * inv, a3.w * inv);
}

// ---------------- gate + residual + LN; xr is col 384 of qkvs ----------------
__global__ void gate_ln(const float* __restrict__ x, const float* __restrict__ att,
                        const float* __restrict__ qkvs, const float* __restrict__ Wb,
                        float* __restrict__ x1, int N)
{
  int wid = threadIdx.x >> 6, lane = threadIdx.x & 63;
  int n = blockIdx.x * 4 + wid;
  if (n >= N) return;
  size_t base = (size_t)n * 128 + lane * 2;
  float2 o = *(const float2*)(att + base);
  float2 r = *(const float2*)(qkvs + (size_t)n * 512 + 384 + lane * 2);
  float2 xv = *(const float2*)(x + base);
  float2 w0 = *(const float2*)(Wb + lane * 2);
  float2 w1 = *(const float2*)(Wb + 128 + lane * 2);
  float2 w2 = *(const float2*)(Wb + 256 + lane * 2);
  float ts = o.x * w0.x + o.y * w0.y + r.x * w1.x + r.y * w1.y
           + (o.x - r.x) * w2.x + (o.y - r.y) * w2.y;
#pragma unroll
  for (int mm = 32; mm >= 1; mm >>= 1) ts += __shfl_xor(ts, mm);
  float beta = 1.f / (1.f + expf(-ts));
  float2 y;
  y.x = xv.x + beta * r.x + (1.f - beta) * o.x;
  y.y = xv.y + beta * r.y + (1.f - beta) * o.y;
  float sm = y.x + y.y;
#pragma unroll
  for (int mm = 32; mm >= 1; mm >>= 1) sm += __shfl_xor(sm, mm);
  float mean = sm * (1.f / 128.f);
  float dx = y.x - mean, dy = y.y - mean;
  float vs = dx * dx + dy * dy;
#pragma unroll
  for (int mm = 32; mm >= 1; mm >>= 1) vs += __shfl_xor(vs, mm);
  float rstd = rsqrtf(vs * (1.f / 128.f) + 1e-5f);
  *(float2*)(x1 + base) = make_float2(dx * rstd, dy * rstd);
}

// ---------------- out = LN(a + b); one wave per row ----------------
__global__ void ln_add(const float* __restrict__ a, const float* __restrict__ b,
                       float* __restrict__ out, int R)
{
  int wid = threadIdx.x >> 6, lane = threadIdx.x & 63;
  int r = blockIdx.x * 4 + wid;
  if (r >= R) return;
  size_t base = (size_t)r * 128 + lane * 2;
  float2 av = *(const float2*)(a + base);
  float2 bv = *(const float2*)(b + base);
  float2 y = make_float2(av.x + bv.x, av.y + bv.y);
  float sm = y.x + y.y;
#pragma unroll
  for (int mm = 32; mm >= 1; mm >>= 1) sm += __shfl_xor(sm, mm);
  float mean = sm * (1.f / 128.f);
  float dx = y.x - mean, dy = y.y - mean;
  float vs = dx * dx + dy * dy;
#pragma unroll
  for (int mm = 32; mm >= 1; mm >>= 1) vs += __shfl_xor(vs, mm);
  float rstd = rsqrtf(vs * (1.f / 128.f) + 1e-5f);
  *(float2*)(out + base) = make_float2(dx * rstd, dy * rstd);
}

// ---------------- global tokens attend over nodes (kv fused layout stride 256) ----------------
__global__ void glob_attn(const float* __restrict__ Qg, const float* __restrict__ kv,
                          float* __restrict__ Og,
                          float* __restrict__ m_gl, float* __restrict__ is_gl, int MAXN)
{
  int blk = blockIdx.x;                 // b*64 + g*8 + h
  int h = blk & 7, g = (blk >> 3) & 7, b = blk >> 6;
  int lane = threadIdx.x;
  const float4* q4 = (const float4*)(Qg + (size_t)(b * NGT + g) * 128 + h * 16);
  float4 q0 = q4[0], q1 = q4[1], q2 = q4[2], q3 = q4[3];
  float m = -3.0e38f, s = 0.f;
  float4 a0 = make_float4(0, 0, 0, 0), a1 = a0, a2 = a0, a3 = a0;
  for (int n = lane; n < MAXN; n += 64) {
    size_t base = ((size_t)(b * MAXN + n)) * 256 + h * 16;
    const float4* k4 = (const float4*)(kv + base);
    float d = dot4(q0, k4[0]) + dot4(q1, k4[1]) + dot4(q2, k4[2]) + dot4(q3, k4[3]);
    d *= 0.25f;
    float mn = fmaxf(m, d);
    float sc = expf(m - mn);
    float p = expf(d - mn);
    const float4* v4 = (const float4*)(kv + base + 128);
    a0 = scale_madd(a0, sc, v4[0], p);
    a1 = scale_madd(a1, sc, v4[1], p);
    a2 = scale_madd(a2, sc, v4[2], p);
    a3 = scale_madd(a3, sc, v4[3], p);
    s = s * sc + p;
    m = mn;
  }
#pragma unroll
  for (int off = 32; off >= 1; off >>= 1) {
    float m2 = __shfl_xor(m, off);
    float s2 = __shfl_xor(s, off);
    float4 c0 = shfl_xor4(a0, off), c1 = shfl_xor4(a1, off);
    float4 c2 = shfl_xor4(a2, off), c3 = shfl_xor4(a3, off);
    float mn = fmaxf(m, m2);
    float e1 = expf(m - mn), e2 = expf(m2 - mn);
    s = s * e1 + s2 * e2;
    a0 = comb4(a0, e1, c0, e2);
    a1 = comb4(a1, e1, c1, e2);
    a2 = comb4(a2, e1, c2, e2);
    a3 = comb4(a3, e1, c3, e2);
    m = mn;
  }
  if (lane == 0) {
    float inv = 1.f / s;
    float4* o4 = (float4*)(Og + (size_t)(b * NGT + g) * 128 + h * 16);
    o4[0] = make_float4(a0.x * inv, a0.y * inv, a0.z * inv, a0.w * inv);
    o4[1] = make_float4(a1.x * inv, a1.y * inv, a1.z * inv, a1.w * inv);
    o4[2] = make_float4(a2.x * inv, a2.y * inv, a2.z * inv, a2.w * inv);
    o4[3] = make_float4(a3.x * inv, a3.y * inv, a3.z * inv, a3.w * inv);
    m_gl[blk] = m;
    is_gl[blk] = inv;
  }
}

// ---------------- P rows (kv stride 256) ----------------
__global__ void pker(const float* __restrict__ Qg, const float* __restrict__ kv,
                     const float* __restrict__ m_gl, const float* __restrict__ is_gl,
                     float* __restrict__ P, int MAXN)
{
  int nchunk = (MAXN + 255) >> 8;
  int b = blockIdx.x / nchunk;
  int ch = blockIdx.x % nchunk;
  __shared__ float qs[4 * 128];
  __shared__ float ms[32], iss[32];
  for (int i = threadIdx.x; i < 512; i += 256)
    qs[i] = Qg[(size_t)(b * NGT + LSTOK) * 128 + i];
  if (threadIdx.x < 32) {
    int g = threadIdx.x >> 3, h = threadIdx.x & 7;
    ms[threadIdx.x]  = m_gl[(b * NGT + LSTOK + g) * H + h];
    iss[threadIdx.x] = is_gl[(b * NGT + LSTOK + g) * H + h];
  }
  __syncthreads();
  int n = ch * 256 + threadIdx.x;
  if (n >= MAXN) return;
  float acc[4] = {0.f, 0.f, 0.f, 0.f};
  size_t kbase = ((size_t)(b * MAXN + n)) * 256;
  for (int h = 0; h < H; h++) {
    const float4* k4 = (const float4*)(kv + kbase + h * 16);
    float4 k0 = k4[0], k1 = k4[1], k2 = k4[2], k3 = k4[3];
#pragma unroll
    for (int g = 0; g < 4; g++) {
      const float4* qp = (const float4*)(qs + g * 128 + h * 16);
      float d = dot4(k0, qp[0]) + dot4(k1, qp[1]) + dot4(k2, qp[2]) + dot4(k3, qp[3]);
      d *= 0.25f;
      acc[g] += expf(d - ms[g * 8 + h]) * iss[g * 8 + h];
    }
  }
#pragma unroll
  for (int g = 0; g < 4; g++)
    P[(size_t)(b * 4 + g) * MAXN + n] = acc[g] * 0.125f;
}

// ---------------- reg: off-diagonal Gram of row-normalized P ----------------
__global__ void regk(const float* __restrict__ P, float* __restrict__ offb, int MAXN)
{
  int b = blockIdx.x;
  int t = threadIdx.x;
  float v[10];
#pragma unroll
  for (int i = 0; i < 10; i++) v[i] = 0.f;
  for (int n = t; n < MAXN; n += 256) {
    float p0 = P[(size_t)(b * 4 + 0) * MAXN + n];
    float p1 = P[(size_t)(b * 4 + 1) * MAXN + n];
    float p2 = P[(size_t)(b * 4 + 2) * MAXN + n];
    float p3 = P[(size_t)(b * 4 + 3) * MAXN + n];
    v[0] += p0; v[1] += p1; v[2] += p2; v[3] += p3;
    v[4] += p0 * p1; v[5] += p0 * p2; v[6] += p0 * p3;
    v[7] += p1 * p2; v[8] += p1 * p3; v[9] += p2 * p3;
  }
#pragma unroll
  for (int i = 0; i < 10; i++) {
    float x = v[i];
#pragma unroll
    for (int mm = 32; mm >= 1; mm >>= 1) x += __shfl_xor(x, mm);
    v[i] = x;
  }
  __shared__ float red[4][10];
  int wid = t >> 6, lane = t & 63;
  if (lane == 0)
    for (int i = 0; i < 10; i++) red[wid][i] = v[i];
  __syncthreads();
  if (t == 0) {
    float r[10];
    for (int i = 0; i < 10; i++) r[i] = red[0][i] + red[1][i] + red[2][i] + red[3][i];
    float r0 = r[0] + 1e-8f, r1 = r[1] + 1e-8f, r2 = r[2] + 1e-8f, r3 = r[3] + 1e-8f;
    float off = 2.f * (r[4] / (r0 * r1) + r[5] / (r0 * r2) + r[6] / (r0 * r3)
                     + r[7] / (r1 * r2) + r[8] / (r1 * r3) + r[9] / (r2 * r3));
    offb[b] = off * (1.f / 12.f);   // (Kt*Kt - Kt) = 12
  }
}

__global__ void regfin(const float* __restrict__ offb, float* __restrict__ out) {
  if (threadIdx.x == 0 && blockIdx.x == 0) {
    float s = 0.f;
    for (int i = 0; i < 8; i++) s += offb[i];
    *out = s * (1.f / 8.f);
  }
}

// ---------------- nodes attend to 8 global tokens; K/V staged in LDS ----------------
// block = 32 nodes x 8 heads; a block touches at most 2 batches.
__global__ void node_attn(const float* __restrict__ Qn, const float* __restrict__ Kg,
                          const float* __restrict__ Vg, float* __restrict__ On,
                          int N, int MAXN)
{
  __shared__ float kg[2][NGT * 128];
  __shared__ float vg[2][NGT * 128];
  int n0 = blockIdx.x * 32;
  int b0 = n0 / MAXN;
  int nlast = n0 + 31; if (nlast >= N) nlast = N - 1;
  int bLast = nlast / MAXN;
  int nb = (bLast != b0) ? 2 : 1;
  for (int bi = 0; bi < nb; ++bi) {
    size_t gb = (size_t)((b0 + bi) * NGT) * 128;
    int i = threadIdx.x * 4;
    *(float4*)&kg[bi][i] = *(const float4*)(Kg + gb + i);
    *(float4*)&vg[bi][i] = *(const float4*)(Vg + gb + i);
  }
  __syncthreads();
  int n = n0 + (threadIdx.x >> 3), h = threadIdx.x & 7;
  if (n >= N) return;
  int bi = (n / MAXN) - b0;
  const float4* q4 = (const float4*)(Qn + (size_t)n * 128 + h * 16);
  float4 q0 = q4[0], q1 = q4[1], q2 = q4[2], q3 = q4[3];
  float l[NGT];
  float mx = -3.0e38f;
#pragma unroll
  for (int tk = 0; tk < NGT; tk++) {
    const float4* k4 = (const float4*)(&kg[bi][tk * 128 + h * 16]);
    float d = dot4(q0, k4[0]) + dot4(q1, k4[1]) + dot4(q2, k4[2]) + dot4(q3, k4[3]);
    l[tk] = d * 0.25f;
    mx = fmaxf(mx, l[tk]);
  }
  float s = 0.f;
#pragma unroll
  for (int tk = 0; tk < NGT; tk++) { l[tk] = expf(l[tk] - mx); s += l[tk]; }
  float inv = 1.f / s;
  float4 a0 = make_float4(0, 0, 0, 0), a1 = a0, a2 = a0, a3 = a0;
#pragma unroll
  for (int tk = 0; tk < NGT; tk++) {
    float p = l[tk] * inv;
    const float4* v4 = (const float4*)(&vg[bi][tk * 128 + h * 16]);
    a0 = scale_madd(a0, 1.f, v4[0], p);
    a1 = scale_madd(a1, 1.f, v4[1], p);
    a2 = scale_madd(a2, 1.f, v4[2], p);
    a3 = scale_madd(a3, 1.f, v4[3], p);
  }
  float4* o4 = (float4*)(On + (size_t)n * 128 + h * 16);
  o4[0] = a0; o4[1] = a1; o4[2] = a2; o4[3] = a3;
}

extern "C" void kernel_launch(void* const* d_in, const int* in_sizes, int n_in,
                              void* d_out, int out_size, void* d_ws, size_t ws_size,
                              hipStream_t stream)
{
  const float* x     = (const float*)d_in[0];
  const int*   ei    = (const int*)d_in[1];
  const float* gh    = (const float*)d_in[2];
  const float* Wq    = (const float*)d_in[6];
  const float* bqv   = (const float*)d_in[7];
  const float* Wk    = (const float*)d_in[8];
  const float* bkv   = (const float*)d_in[9];
  const float* Wv    = (const float*)d_in[10];
  const float* bvv   = (const float*)d_in[11];
  const float* Wsk   = (const float*)d_in[12];
  const float* bsk   = (const float*)d_in[13];
  const float* Wbeta = (const float*)d_in[14];
  const float* ngw   = (const float*)d_in[15];
  const float* ngb   = (const float*)d_in[16];
  const float* ngow  = (const float*)d_in[17];
  const float* ngob  = (const float*)d_in[18];
  const float* gnw   = (const float*)d_in[19];
  const float* gnb   = (const float*)d_in[20];
  const float* gnow  = (const float*)d_in[21];
  const float* gnob  = (const float*)d_in[22];
  const float* W1    = (const float*)d_in[23];
  const float* b1v   = (const float*)d_in[24];
  const float* W2    = (const float*)d_in[25];
  const float* b2v   = (const float*)d_in[26];

  const int N    = in_sizes[0] / D;   // 50000
  const int E    = in_sizes[1] / 2;   // 400000
  const int Bb   = 8;
  const int MAXN = N / Bb;            // 6250

  const int* srcI = ei;
  const int* dstI = ei + E;

  size_t ND = (size_t)N * D;
  float* fw = (float*)d_ws;
  float* qkvs = fw;                   // N x 512 (also: kv N x 256 at +0 later, etc.)
  float* wx1  = fw + 4 * ND;          // x1 / x2; kvb (bf16) aliases this region pre-gate_ln
  short* kvb  = (short*)wx1;          // N x 256 bf16
  float* misc = fw + 5 * ND;
  float* Qg    = misc;                // 64*128
  float* Og    = Qg + 8192;
  float* gout  = Og + 8192;
  float* Kg    = gout + 8192;
  float* Vg    = Kg + 8192;
  float* m_gl  = Vg + 8192;           // 512
  float* is_gl = m_gl + 512;          // 512
  float* Pbuf  = is_gl + 512;         // 8*4*MAXN
  float* offb  = Pbuf + (size_t)Bb * 4 * MAXN;   // 8 (+pad)
  float* bias512 = offb + 16;         // 512
  int* deg       = (int*)(bias512 + 512);
  int* row_start = deg + N;           // N+1
  int* cursor    = row_start + N + 1;
  int* bsum      = cursor + N;        // <=1024
  int* edge_list = bsum + 1024;       // E
  short* wbase = (short*)((((uintptr_t)(edge_list + E)) + 15) & ~(uintptr_t)15);
  short* cWq  = wbase;            // 4 x 128x128 stacked -> 512x128
  short* cWk  = cWq  + 16384;
  short* cWv  = cWk  + 16384;
  short* cWsk = cWv  + 16384;
  short* cNgK = cWsk + 16384;     // 2 x 128x128 stacked -> 256x128
  short* cNgV = cNgK + 16384;
  short* cGnQ = cNgV + 16384;
  short* cGnO = cGnQ + 16384;
  short* cW1  = cGnO + 16384;     // 256x128
  short* cW2  = cW1  + 32768;     // 128x256

  float* outx   = (float*)d_out;
  float* outgh  = outx + ND;                       // 8192
  float* outreg = outgh + (size_t)Bb * NGT * D;    // 1
  float* wa     = outx;   // scratch: tconv att-out, later out-proj result

  const int GXM = (N + 127) / 128;    // 391
  const int SB  = (N + 1023) / 1024;  // 49
  dim3 blk256(256);

  // one-shot weight conversion + bias concat
  CvtArgs ca;
  ca.s[0] = Wq;   ca.d[0] = cWq;  ca.n[0] = 16384;
  ca.s[1] = Wk;   ca.d[1] = cWk;  ca.n[1] = 16384;
  ca.s[2] = Wv;   ca.d[2] = cWv;  ca.n[2] = 16384;
  ca.s[3] = Wsk;  ca.d[3] = cWsk; ca.n[3] = 16384;
  ca.s[4] = ngw + 128 * 128; ca.d[4] = cNgK; ca.n[4] = 16384;
  ca.s[5] = ngw + 256 * 128; ca.d[5] = cNgV; ca.n[5] = 16384;
  ca.s[6] = gnw;  ca.d[6] = cGnQ; ca.n[6] = 16384;
  ca.s[7] = gnow; ca.d[7] = cGnO; ca.n[7] = 16384;
  ca.s[8] = W1;   ca.d[8] = cW1;  ca.n[8] = 32768;
  ca.s[9] = W2;   ca.d[9] = cW2;  ca.n[9] = 32768;
  cvt_weights<<<dim3(32, 10), blk256, 0, stream>>>(ca);
  concat_bias4<<<dim3(1), dim3(128), 0, stream>>>(bqv, bkv, bvv, bsk, bias512);

  // CSR build
  hipMemsetAsync(deg, 0, (size_t)N * sizeof(int), stream);
  count_deg<<<dim3((E + 255) / 256), blk256, 0, stream>>>(dstI, deg, E);
  scan_pass1<<<dim3(SB), blk256, 0, stream>>>(deg, bsum, N);
  scan_pass2<<<dim3(1), dim3(1024), 0, stream>>>(bsum, SB);
  scan_pass3<<<dim3(SB), blk256, 0, stream>>>(deg, bsum, row_start, cursor, N, E);
  fill_edges<<<dim3((E + 255) / 256), blk256, 0, stream>>>(dstI, cursor, edge_list, E);

  // fused tconv projections: qkvs = x @ [Wq;Wk;Wv;Wskip]^T + bias512 (N x 512)
  // + bf16 side-channel of cols [128,384) -> kvb (k|v packed)
  gemm_mfma<<<dim3(GXM, 4), blk256, 0, stream>>>(x, cWq, bias512, qkvs, N, 128, 512, 0,
                                                 kvb, 128);

  // edge attention + gate + LN  -> x1
  tconv_attn<<<dim3((N * H + 255) / 256), blk256, 0, stream>>>(qkvs, kvb, row_start, edge_list, srcI, wa, N);
  gate_ln<<<dim3((N + 3) / 4), blk256, 0, stream>>>(x, wa, qkvs, Wbeta, wx1, N);

  // global MHA: fused K|V projection (N x 256)
  gemm_mfma<<<dim3(GXM, 2), blk256, 0, stream>>>(wx1, cNgK, ngb + 128, fw, N, 128, 256, 0,
                                                 nullptr, 0);
  gemm_small<<<dim3(64), dim3(128), 0, stream>>>(gh, ngw, ngb, Qg, 64);
  glob_attn<<<dim3(512), dim3(64), 0, stream>>>(Qg, fw, Og, m_gl, is_gl, MAXN);
  pker<<<dim3(8 * ((MAXN + 255) / 256)), blk256, 0, stream>>>(Qg, fw, m_gl, is_gl, Pbuf, MAXN);
  regk<<<dim3(8), blk256, 0, stream>>>(Pbuf, offb, MAXN);
  regfin<<<dim3(1), dim3(64), 0, stream>>>(offb, outreg);

  gemm_small<<<dim3(64), dim3(128), 0, stream>>>(Og, ngow, ngob, gout, 64);
  ln_add<<<dim3(16), blk256, 0, stream>>>(gh, gout, outgh, 64);   // new global_h

  // nodes attend to global tokens
  gemm_small<<<dim3(64), dim3(128), 0, stream>>>(outgh, gnw + 128 * 128, gnb + 128, Kg, 64);
  gemm_small<<<dim3(64), dim3(128), 0, stream>>>(outgh, gnw + 256 * 128, gnb + 256, Vg, 64);
  gemm_mfma<<<dim3(GXM, 1), blk256, 0, stream>>>(wx1, cGnQ, gnb, fw + 2 * ND, N, 128, 128, 0,
                                                 nullptr, 0);  // Qn
  node_attn<<<dim3((N + 31) / 32), blk256, 0, stream>>>(fw + 2 * ND, Kg, Vg, fw + 3 * ND, N, MAXN);
  gemm_mfma<<<dim3(GXM, 1), blk256, 0, stream>>>(fw + 3 * ND, cGnO, gnob, wa, N, 128, 128, 0,
                                                 nullptr, 0);  // out proj
  ln_add<<<dim3((N + 3) / 4), blk256, 0, stream>>>(wx1, wa, wx1, N);   // x2 (in place)

  // FF + final LN -> d_out x
  gemm_mfma<<<dim3(GXM, 2), blk256, 0, stream>>>(wx1, cW1, b1v, fw, N, 128, 256, 1,
                                                 nullptr, 0);          // ff1
  gemm_mfma<<<dim3(GXM, 1), blk256, 0, stream>>>(fw, cW2, b2v, fw + 2 * ND, N, 256, 128, 0,
                                                 nullptr, 0);          // ff2
  ln_add<<<dim3((N + 3) / 4), blk256, 0, stream>>>(wx1, fw + 2 * ND, outx, N);
}